// Round 1
// baseline (280.820 us; speedup 1.0000x reference)
//
#include <hip/hip_runtime.h>
#include <math.h>

#define B_   16
#define V_   16
#define C_   64
#define M_   32
#define CM_  16
#define D_   128
#define OUT_ 600
#define NSEQ 256      // B*V
#define NROW 8192     // B*V*M

typedef __attribute__((ext_vector_type(8))) short bf16x8;
typedef __attribute__((ext_vector_type(4))) short bf16x4;
typedef __attribute__((ext_vector_type(4))) float f32x4;

__device__ __forceinline__ unsigned short f2bf(float x) {
  union { float f; unsigned u; } v; v.f = x;
  unsigned r = v.u + 0x7fff + ((v.u >> 16) & 1);   // RNE
  return (unsigned short)(r >> 16);
}
__device__ __forceinline__ float bf2f(short s) {
  union { unsigned u; float f; } v;
  v.u = ((unsigned)(unsigned short)s) << 16;
  return v.f;
}
__device__ __forceinline__ float u2f(unsigned u) {
  union { unsigned u; float f; } v; v.u = u; return v.f;
}
// fast sigmoid / tanh: native v_exp + v_rcp (~5 inst), saturate correctly
__device__ __forceinline__ float fsig(float x)  { return __fdividef(1.f, 1.f + __expf(-x)); }
__device__ __forceinline__ float ftanh(float x) { return 1.f - 2.f*__fdividef(1.f, __expf(2.f*x) + 1.f); }

// ---- workspace layout (float units; bf16 arrays are short* views) ----
constexpr int OFF_VIS   = 0;                               // fp32 [3][256][128]
constexpr int OFF_VISB  = 98304;                           // bf16 [3][256][128]
constexpr int OFF_MONB  = 147456;                          // bf16 [2][8192][128]
constexpr int OFF_TOTB  = 1196032;                         // bf16 [2][8192][128]
constexpr int OFF_W12T  = 2244608;                         // bf16 [8][128n][256k]
constexpr int OFF_WIHB  = 2375680;                         // bf16 [5][384n][128k]
constexpr int OFF_WIHTV = 2498560;                         // fp32 [4][128][384]
constexpr int OFF_XE    = 2695168;                         // fp32 [2][256][128]
constexpr int OFF_GI    = 2760704;                         // bf16 gi3[8][64][32][384][4]
constexpr int OFF_LAST  = 27926528;                        // fp32 [8][256][128]
constexpr int OFF_VH    = 29171712;                        // fp32 [10][16][128]

// =====================================================================
// prep+vis merged — verified round 16, unchanged.
// =====================================================================
__global__ __launch_bounds__(256) void k_prepvis(
    const float* __restrict__ Wself, const float* __restrict__ Wmsg,
    const float* __restrict__ mWih,  const float* __restrict__ vWih,
    const float* __restrict__ wgt,   const float* __restrict__ age,
    const float* __restrict__ fwW,   const float* __restrict__ fwB,
    const float* __restrict__ faW,   const float* __restrict__ faB,
    const int* __restrict__ cc, const int* __restrict__ cp, const int* __restrict__ cd,
    const float* __restrict__ ec, const float* __restrict__ ep, const float* __restrict__ ed,
    short* __restrict__ w12t, short* __restrict__ wihb,
    float* __restrict__ wihTv, float* __restrict__ xe,
    float* __restrict__ vis, short* __restrict__ visb)
{
  int bx = blockIdx.x, tid = threadIdx.x;
  if (bx < 1024) {                      // w12t[pt][n][k] = bf16 combined
    int lin = bx*256 + tid;             // < 262144
    int pt = lin >> 15, rem = lin & 32767;
    int n = rem >> 8, k = rem & 255;
    float v;
    if (k < 128) v = Wself[pt*16384 + k*128 + n] - Wmsg[pt*16384 + k*128 + n]*(1.f/3.f);
    else         v = Wmsg[pt*16384 + (k-128)*128 + n]*(1.f/3.f);
    w12t[lin] = (short)f2bf(v);
  } else if (bx < 1984) {               // wihb = bf16(mWih) elementwise
    int lin = (bx-1024)*256 + tid;      // < 245760
    wihb[lin] = (short)f2bf(mWih[lin]);
  } else if (bx < 2752) {               // vgru Wih transpose fp32
    int lin = (bx-1984)*256 + tid;      // < 196608
    int g = lin / 49152, rem2 = lin % 49152;
    int k = rem2 / 384, j = rem2 % 384;
    wihTv[lin] = vWih[g*49152 + j*128 + k];
  } else if (bx < 3008) {               // xe for weight / age
    int lin = (bx-2752)*256 + tid;      // < 65536
    int which = lin >> 15, rem2 = lin & 32767;
    int n = rem2 >> 7, d = rem2 & 127;
    float x  = which ? age[n] : wgt[n];
    float Wv = which ? faW[d] : fwW[d];
    float bb = which ? faB[d] : fwB[d];
    xe[lin] = (x != 0.0f) ? (x*Wv + bb) : 0.0f;
  } else {                              // visit-event sum pools
    int idx = (bx-3008)*256 + tid;      // < 98304
    int type = idx >> 15;
    int r = idx & 32767;
    int bv = r >> 7, d = r & 127;
    const int*   codes = (type==0) ? cc : (type==1) ? cp : cd;
    const float* emb   = (type==0) ? ec : (type==1) ? ep : ed;
    float acc = 0.f;
    for (int c = 0; c < C_; ++c) {
      int code = codes[bv*C_ + c];
      acc += emb[code*D_ + d];
    }
    vis [(type*NSEQ + bv)*D_ + d] = acc;
    visb[(type*NSEQ + bv)*D_ + d] = (short)f2bf(acc);
  }
}

// =====================================================================
// monitor-event pools — unchanged (verified).
// =====================================================================
__global__ __launch_bounds__(128) void k_mon(
    const int* __restrict__ cli, const int* __restrict__ clv,
    const int* __restrict__ cii, const int* __restrict__ civ,
    const float* __restrict__ eli, const float* __restrict__ elv,
    const float* __restrict__ eii, const float* __restrict__ eiv,
    const float* __restrict__ vis,
    short* __restrict__ monb, short* __restrict__ totb)
{
  int p   = blockIdx.x >> 13;
  int bvm = blockIdx.x & 8191;
  int d   = threadIdx.x;
  const int* ci = p ? cii : cli;  const int* cv = p ? civ : clv;
  const float* ei = p ? eii : eli; const float* ev = p ? eiv : elv;
  float acc = 0.f;
  #pragma unroll
  for (int c = 0; c < CM_; ++c) {
    int iv = ci[bvm*CM_ + c];
    int vv = cv[bvm*CM_ + c];
    acc += ei[iv*D_ + d] * ev[vv*D_ + d];
  }
  int bv = bvm >> 5;
  float vsum = vis[bv*D_ + d] + vis[(NSEQ + bv)*D_ + d] + vis[(2*NSEQ + bv)*D_ + d];
  monb[(p*NROW + bvm)*D_ + d] = (short)f2bf(acc);
  totb[(p*NROW + bvm)*D_ + d] = (short)f2bf(acc + vsum);
}

// =====================================================================
// FUSED GNN+GI (MFMA bf16) — verified, unchanged.
// =====================================================================
__global__ __launch_bounds__(256, 4) void k_gg(
    const short* __restrict__ monb, const short* __restrict__ totb,
    const short* __restrict__ visb, const short* __restrict__ w12t,
    const short* __restrict__ wihb, const float* __restrict__ mbih,
    short* __restrict__ gi)
{
  const int pt = blockIdx.x >> 6;          // run 0..7
  const int rb = blockIdx.x & 63;
  const int p = pt >> 2, t = pt & 3;
  const int g = (pt % 4 == 0) ? (pt / 4) : (pt % 4 + 1);
  const int row0 = rb * 128;
  const int tid = threadIdx.x;
  const int w = tid >> 6, lane = tid & 63;
  const int c = lane & 15, q = lane >> 4;

  __shared__ short smem[2*128*72];         // 36864 B; Ys / giS alias
  short (*Xs)[72]  = (short(*)[72])smem;
  short (*Ws)[72]  = (short(*)[72])(smem + 128*72);
  short (*Ys)[136] = (short(*)[136])smem;
  float (*giS)[68] = (float(*)[68])smem;   // 128 x 68 fp32 = 34816 B

  const int rowL = tid >> 1, kc = tid & 1;
  const int rowG = row0 + rowL;
  const int bv = rowG >> 5;
  const int mg = w >> 1, ng = w & 1;

  f32x4 acc1[4][4];
  #pragma unroll
  for (int mi = 0; mi < 4; ++mi)
    #pragma unroll
    for (int ni = 0; ni < 4; ++ni) acc1[mi][ni] = (f32x4){0.f,0.f,0.f,0.f};

  const short* featp = (t == 0) ? (monb + ((size_t)p*NROW + rowG)*128)
                                : (visb + ((size_t)(t-1)*NSEQ + bv)*128);
  const short* totp  = totb + ((size_t)p*NROW + rowG)*128;
  const short* wrow  = w12t + ((size_t)pt*128 + rowL)*256;

  #pragma unroll 1
  for (int ks = 0; ks < 4; ++ks) {
    __syncthreads();
    int kg = ks*64 + kc*32;
    const short* srcX = (kg < 128) ? (featp + kg) : (totp + (kg - 128));
    const short* srcW = wrow + kg;
    short* dX = &Xs[rowL][kc*32];
    short* dW = &Ws[rowL][kc*32];
    #pragma unroll
    for (int i = 0; i < 4; ++i) {
      *(bf16x8*)(dX + 8*i) = *(const bf16x8*)(srcX + 8*i);
      *(bf16x8*)(dW + 8*i) = *(const bf16x8*)(srcW + 8*i);
    }
    __syncthreads();
    #pragma unroll
    for (int kk = 0; kk < 2; ++kk) {
      bf16x8 af[4], bfr[4];
      #pragma unroll
      for (int mi = 0; mi < 4; ++mi)
        af[mi] = *(const bf16x8*)&Xs[(mg*4+mi)*16 + c][kk*32 + q*8];
      #pragma unroll
      for (int ni = 0; ni < 4; ++ni)
        bfr[ni] = *(const bf16x8*)&Ws[(ng*4+ni)*16 + c][kk*32 + q*8];
      #pragma unroll
      for (int mi = 0; mi < 4; ++mi)
        #pragma unroll
        for (int ni = 0; ni < 4; ++ni)
          acc1[mi][ni] = __builtin_amdgcn_mfma_f32_16x16x32_bf16(af[mi], bfr[ni], acc1[mi][ni], 0, 0, 0);
    }
  }
  __syncthreads();     // done reading Xs/Ws (Ys aliases them)

  // relu + C-layout (col=lane&15, row=(lane>>4)*4+reg) -> Ys[row][col] bf16
  #pragma unroll
  for (int mi = 0; mi < 4; ++mi)
    #pragma unroll
    for (int ni = 0; ni < 4; ++ni)
      #pragma unroll
      for (int reg = 0; reg < 4; ++reg)
        Ys[(mg*4+mi)*16 + q*4 + reg][(ng*4+ni)*16 + c] =
            (short)f2bf(fmaxf(acc1[mi][ni][reg], 0.f));
  __syncthreads();

  // ---- stage 2: gi = Y @ Wih^T + bih ----
  bf16x8 Af[2][4];
  #pragma unroll
  for (int mi = 0; mi < 2; ++mi)
    #pragma unroll
    for (int kt = 0; kt < 4; ++kt)
      Af[mi][kt] = *(const bf16x8*)&Ys[(w*2+mi)*16 + c][kt*32 + q*8];

  float bihv[24];
  #pragma unroll
  for (int nt = 0; nt < 24; ++nt)
    bihv[nt] = mbih[g*384 + nt*16 + c];

  short* gslab = gi + (((size_t)pt*64 + rb)*32)*384*4;   // bf16 [m][col][s4]
  #pragma unroll 1
  for (int cn = 0; cn < 6; ++cn) {
    f32x4 acc2[2][4];
    #pragma unroll
    for (int mi = 0; mi < 2; ++mi)
      #pragma unroll
      for (int ni = 0; ni < 4; ++ni) acc2[mi][ni] = (f32x4){0.f,0.f,0.f,0.f};
    #pragma unroll
    for (int ni = 0; ni < 4; ++ni) {
      int n = (cn*4 + ni)*16 + c;
      const short* bp_ = wihb + ((size_t)g*384 + n)*128 + q*8;
      #pragma unroll
      for (int kt = 0; kt < 4; ++kt) {
        bf16x8 bfr = *(const bf16x8*)(bp_ + kt*32);
        #pragma unroll
        for (int mi = 0; mi < 2; ++mi)
          acc2[mi][ni] = __builtin_amdgcn_mfma_f32_16x16x32_bf16(Af[mi][kt], bfr, acc2[mi][ni], 0, 0, 0);
      }
    }
    __syncthreads();
    #pragma unroll
    for (int mi = 0; mi < 2; ++mi)
      #pragma unroll
      for (int ni = 0; ni < 4; ++ni) {
        float bia = bihv[cn*4+ni];
        #pragma unroll
        for (int reg = 0; reg < 4; ++reg)
          giS[(w*2+mi)*16 + q*4 + reg][ni*16 + c] = acc2[mi][ni][reg] + bia;
      }
    __syncthreads();
    #pragma unroll
    for (int k = 0; k < 8; ++k) {
      int o4 = tid + k*256;            // 0..2047
      int m = o4 >> 6, colL = o4 & 63;
      bf16x4 v;
      v[0] = (short)f2bf(giS[m][colL]);
      v[1] = (short)f2bf(giS[32+m][colL]);
      v[2] = (short)f2bf(giS[64+m][colL]);
      v[3] = (short)f2bf(giS[96+m][colL]);
      *(bf16x4*)&gslab[((size_t)m*384 + cn*64 + colL)*4] = v;
    }
  }
}

// =====================================================================
// monitor-level GRU v7 — RESTRUCTURED this round.
// Old: 256 blocks x 512 thr, 8 seq/block (half of MFMA M wasted),
//      activation on 32/64 lanes x 4 regs -> t_step ~4000 cyc, 54 us.
// New: 128 blocks x 1024 thr (16 waves = 4 waves/SIMD), 16 seq/block
//      (full MFMA M), N=384 split over 12 waves (8 MFMA each, gate-
//      aligned), gate pre-activations staged in padded LDS gS[384][20],
//      activation spread over ALL 1024 lanes (2 h-items each).
// Per-step issue per SIMD roughly halves and latency hiding doubles.
// =====================================================================
__global__ __launch_bounds__(1024) void k_mgru(
    const short* __restrict__ gi, const float* __restrict__ mWhh,
    const float* __restrict__ mbhh, float* __restrict__ last)
{
  const int run  = blockIdx.x >> 4;     // 0..7
  const int pair = blockIdx.x & 15;     // 0..15 == batch index b (16 seq = 16 visits)
  const int g = (run % 4 == 0) ? (run / 4) : (run % 4 + 1);
  const int tid = threadIdx.x;
  const int w = tid >> 6;               // wave 0..15
  const int lane = tid & 63;
  const int c = lane & 15, q = lane >> 4;

  __shared__ short hb[2][4][16][40];    // [buf][kt][seq][kk] bf16, 10240 B
  __shared__ float gS[384][20];         // [gate-col][seq(16)+pad4] fp32, 30720 B

  for (int idx = tid; idx < 2*4*16*40; idx += 1024)
    ((short*)hb)[idx] = 0;

  // ---- MFMA waves: w 0..11; wave covers cols [gate*128 + nt*32, +32) ----
  const bool mfw = (w < 12);
  const int gate_w = w >> 2;            // 0..2
  const int nt = w & 3;                 // 0..3
  bf16x8 bfrag[2][4];
  if (mfw) {
    #pragma unroll
    for (int ti = 0; ti < 2; ++ti) {
      const int col = gate_w*128 + nt*32 + ti*16 + c;
      const float* wp = mWhh + ((size_t)g*384 + col)*128 + q*8;
      #pragma unroll
      for (int kt = 0; kt < 4; ++kt) {
        float4 lo = *(const float4*)(wp + kt*32);
        float4 hi = *(const float4*)(wp + kt*32 + 4);
        bf16x8 tt;
        tt[0]=(short)f2bf(lo.x); tt[1]=(short)f2bf(lo.y); tt[2]=(short)f2bf(lo.z); tt[3]=(short)f2bf(lo.w);
        tt[4]=(short)f2bf(hi.x); tt[5]=(short)f2bf(hi.y); tt[6]=(short)f2bf(hi.z); tt[7]=(short)f2bf(hi.w);
        bfrag[ti][kt] = tt;
      }
    }
  }

  // ---- activation mapping: lane owns hidden j for seqs (s0, s0+1) ----
  const int j  = tid >> 3;              // 0..127
  const int sp = tid & 7;               // 0..7
  const int s0 = sp*2;                  // even seq
  const int ktj = j >> 5, kkj = j & 31;
  const float bh0 = mbhh[g*384 +       j];
  const float bh1 = mbhh[g*384 + 128 + j];
  const float bh2 = mbhh[g*384 + 256 + j];
  // gi (bf16) element: idx = (((run*64 + pair*4 + quad)*32 + m)*384 + gate*128 + j)*4 + (s&3)
  const short* gip = gi + (((size_t)run*64 + pair*4 + (s0>>2))*32)*384*4
                        + (size_t)j*4 + (s0&3);
  // per-load add: gate*512 (shorts) ; per-step add: m*1536 (shorts)

  float h0 = 0.f, h1 = 0.f;

  unsigned gA[3], gB[3];
  #pragma unroll
  for (int gate = 0; gate < 3; ++gate)
    gA[gate] = *(const unsigned*)(gip + gate*512);
  __syncthreads();

  auto step = [&](int m, unsigned (&gcur)[3], unsigned (&gnext)[3]) {
    const int cur = m & 1, nxt = cur ^ 1;
    if (mfw) {
      bf16x8 a[4];
      #pragma unroll
      for (int kt = 0; kt < 4; ++kt)
        a[kt] = *(const bf16x8*)&hb[cur][kt][c][q*8];   // A[seq=c][k]
      #pragma unroll
      for (int ti = 0; ti < 2; ++ti) {
        f32x4 acc = (f32x4){0.f,0.f,0.f,0.f};
        #pragma unroll
        for (int kt = 0; kt < 4; ++kt)
          acc = __builtin_amdgcn_mfma_f32_16x16x32_bf16(a[kt], bfrag[ti][kt], acc, 0, 0, 0);
        const int col = gate_w*128 + nt*32 + ti*16 + c;
        *(f32x4*)&gS[col][q*4] = acc;                    // rows seq q*4..q*4+3
      }
    }
    __syncthreads();   // gS(m) ready; also guards gS reuse vs last step's reads

    // ---- activation: all 1024 lanes, 2 items each ----
    float2 vr = *(const float2*)&gS[      j][s0];
    float2 vz = *(const float2*)&gS[128 + j][s0];
    float2 vn = *(const float2*)&gS[256 + j][s0];
    if (m < 31) {
      const short* gp = gip + (size_t)(m+1)*1536;
      #pragma unroll
      for (int gate = 0; gate < 3; ++gate)
        gnext[gate] = *(const unsigned*)(gp + gate*512);
    }
    float gi0a = u2f(gcur[0] << 16), gi0b = u2f(gcur[0] & 0xffff0000u);
    float gi1a = u2f(gcur[1] << 16), gi1b = u2f(gcur[1] & 0xffff0000u);
    float gi2a = u2f(gcur[2] << 16), gi2b = u2f(gcur[2] & 0xffff0000u);

    float r0 = fsig(vr.x + bh0 + gi0a);
    float z0 = fsig(vz.x + bh1 + gi1a);
    float n0 = ftanh(gi2a + r0*(vn.x + bh2));
    h0 = (1.f - z0)*n0 + z0*h0;
    float r1 = fsig(vr.y + bh0 + gi0b);
    float z1 = fsig(vz.y + bh1 + gi1b);
    float n1 = ftanh(gi2b + r1*(vn.y + bh2));
    h1 = (1.f - z1)*n1 + z1*h1;

    hb[nxt][ktj][s0    ][kkj] = (short)f2bf(h0);
    hb[nxt][ktj][s0 + 1][kkj] = (short)f2bf(h1);
    __syncthreads();   // hb(nxt) visible for step m+1's MFMA reads
  };

  #pragma unroll 1
  for (int m2 = 0; m2 < 16; ++m2) {
    step(2*m2,     gA, gB);
    step(2*m2 + 1, gB, gA);
  }

  last[((size_t)run*NSEQ + pair*16 + s0    )*D_ + j] = h0;
  last[((size_t)run*NSEQ + pair*16 + s0 + 1)*D_ + j] = h1;
}

// =====================================================================
// visit-level GRU v3 (vgi fused) — verified round 16, unchanged.
// =====================================================================
__global__ __launch_bounds__(768) void k_vgru(
    const float* __restrict__ last, const float* __restrict__ xe,
    const float* __restrict__ wihTv, const float* __restrict__ vbih,
    const float* __restrict__ vWhh, const float* __restrict__ vbhh,
    float* __restrict__ vh)
{
  int run = blockIdx.x >> 4, b = blockIdx.x & 15;
  int tid = threadIdx.x;
  int vidx = (run < 4) ? 0 : (run < 8) ? 1 : (run - 6);

  __shared__ float Xs[16][128];          // 8 KB
  __shared__ float giL[16*384];          // 24 KB
  __shared__ __align__(16) float hsv[128];
  __shared__ float gh[384];

  const float* X = (run < 8) ? (last + ((size_t)run*NSEQ + b*16)*D_)
                             : (xe + ((size_t)(run-8)*NSEQ + b*16)*D_);
  for (int idx = tid; idx < 2048; idx += 768)
    ((float*)Xs)[idx] = X[idx];
  if (tid < 128) hsv[tid] = 0.f;
  __syncthreads();

  // ---- gi precompute into LDS: thread (half, j) does 8 visits ----
  {
    int half = (tid >= 384) ? 1 : 0;
    int j = tid - half*384;
    float accv[8];
    float bias = vbih[vidx*384 + j];
    #pragma unroll
    for (int s = 0; s < 8; ++s) accv[s] = bias;
    const float* W = wihTv + vidx*49152 + j;
    #pragma unroll 4
    for (int k = 0; k < 128; ++k) {
      float wv = W[k*384];
      #pragma unroll
      for (int s = 0; s < 8; ++s) accv[s] += Xs[half*8 + s][k] * wv;
    }
    #pragma unroll
    for (int s = 0; s < 8; ++s)
      giL[(half*8 + s)*384 + j] = accv[s];
  }

  // ---- recurrence weights (pair-split, w[64]/thread, no spill) ----
  int j = tid >> 1, kh = tid & 1;
  float w[64];
  const float4* wrow = (const float4*)(vWhh + (vidx*384 + j)*128 + kh*64);
  #pragma unroll
  for (int k4 = 0; k4 < 16; ++k4) {
    float4 t4 = wrow[k4];
    w[4*k4] = t4.x; w[4*k4+1] = t4.y; w[4*k4+2] = t4.z; w[4*k4+3] = t4.w;
  }
  float bj = vbhh[vidx*384 + j];
  __syncthreads();

  #pragma unroll 1
  for (int v = 0; v < 16; ++v) {
    const float4* h4 = (const float4*)(hsv + kh*64);
    float p0 = 0.f, p1 = 0.f;
    #pragma unroll
    for (int k4 = 0; k4 < 8; ++k4) {
      float4 u0 = h4[k4], u1 = h4[k4+8];
      p0 += w[4*k4   ]*u0.x + w[4*k4+1 ]*u0.y + w[4*k4+2 ]*u0.z + w[4*k4+3 ]*u0.w;
      p1 += w[4*k4+32]*u1.x + w[4*k4+33]*u1.y + w[4*k4+34]*u1.z + w[4*k4+35]*u1.w;
    }
    float part = p0 + p1;
    part += __shfl_xor(part, 1);
    if (kh == 0) gh[j] = bj + ((j < 256) ? giL[v*384 + j] : 0.f) + part;
    __syncthreads();
    if (tid < 128) {
      float r = fsig(gh[tid]);
      float z = fsig(gh[tid+128]);
      float gin = giL[v*384 + 256 + tid];
      float n = ftanh(gin + r*gh[tid+256]);
      hsv[tid] = (1.f - z)*n + z*hsv[tid];
    }
    __syncthreads();
  }
  if (tid < 128) vh[(run*16 + b)*D_ + tid] = hsv[tid];
}

// =====================================================================
// head v4 (pe fused) — verified round 16, unchanged.
// =====================================================================
__global__ __launch_bounds__(256) void k_head(
    const float* __restrict__ vh, const float* __restrict__ Wp,
    const float* __restrict__ bp, float* __restrict__ out)
{
  const int o = blockIdx.x;
  const int tid = threadIdx.x;
  const int b = tid & 15, kc = tid >> 4;
  const int a1[7] = {0,1,2,3,4,8,9};
  const int a2[7] = {-1,5,6,7,-1,-1,-1};
  const float4* wb = (const float4*)(Wp + (size_t)o*896 + kc*56);
  float acc = 0.f;
  #pragma unroll
  for (int i = 0; i < 14; ++i) {
    int cc2 = kc*56 + i*4;
    int s = cc2 >> 7, d0 = cc2 & 127;
    float4 a = *(const float4*)(vh + (a1[s]*16 + b)*D_ + d0);
    int s2 = a2[s];
    if (s2 >= 0) {
      float4 a2v = *(const float4*)(vh + (s2*16 + b)*D_ + d0);
      a.x += a2v.x; a.y += a2v.y; a.z += a2v.z; a.w += a2v.w;
    }
    a.x = fmaxf(a.x, 0.f); a.y = fmaxf(a.y, 0.f);
    a.z = fmaxf(a.z, 0.f); a.w = fmaxf(a.w, 0.f);
    float4 ww = wb[i];
    acc += a.x*ww.x + a.y*ww.y + a.z*ww.z + a.w*ww.w;
  }
  __shared__ float red[16][17];
  red[kc][b] = acc;
  __syncthreads();
  if (tid < 16) {
    float s = 0.f;
    #pragma unroll
    for (int k = 0; k < 16; ++k) s += red[k][tid];
    out[tid*OUT_ + o] = s + bp[o];
  }
}

// =====================================================================
extern "C" void kernel_launch(void* const* d_in, const int* in_sizes, int n_in,
                              void* d_out, int out_size, void* d_ws, size_t ws_size,
                              hipStream_t stream)
{
  (void)in_sizes; (void)n_in; (void)out_size; (void)ws_size;
  const int*   cc   = (const int*)  d_in[0];
  const int*   cp   = (const int*)  d_in[1];
  const int*   cd   = (const int*)  d_in[2];
  const int*   cli  = (const int*)  d_in[3];
  const int*   clv  = (const int*)  d_in[4];
  const int*   cii  = (const int*)  d_in[5];
  const int*   civ  = (const int*)  d_in[6];
  const float* wgt  = (const float*)d_in[7];
  const float* age  = (const float*)d_in[8];
  const float* ec   = (const float*)d_in[9];
  const float* ep   = (const float*)d_in[10];
  const float* ed   = (const float*)d_in[11];
  const float* eli  = (const float*)d_in[12];
  const float* elv  = (const float*)d_in[13];
  const float* eii  = (const float*)d_in[14];
  const float* eiv  = (const float*)d_in[15];
  const float* mWih = (const float*)d_in[16];
  const float* mWhh = (const float*)d_in[17];
  const float* mbih = (const float*)d_in[18];
  const float* mbhh = (const float*)d_in[19];
  const float* vWih = (const float*)d_in[20];
  const float* vWhh = (const float*)d_in[21];
  const float* vbih = (const float*)d_in[22];
  const float* vbhh = (const float*)d_in[23];
  const float* Wself= (const float*)d_in[24];
  const float* Wmsg = (const float*)d_in[25];
  const float* fwW  = (const float*)d_in[26];
  const float* fwB  = (const float*)d_in[27];
  const float* faW  = (const float*)d_in[28];
  const float* faB  = (const float*)d_in[29];
  const float* Wp   = (const float*)d_in[30];
  const float* bp   = (const float*)d_in[31];
  float* out = (float*)d_out;
  float* ws  = (float*)d_ws;

  float* vis   = ws + OFF_VIS;
  short* visb  = (short*)(ws + OFF_VISB);
  short* monb  = (short*)(ws + OFF_MONB);
  short* totb  = (short*)(ws + OFF_TOTB);
  short* w12t  = (short*)(ws + OFF_W12T);
  short* wihb  = (short*)(ws + OFF_WIHB);
  float* wihTv = ws + OFF_WIHTV;
  float* xe    = ws + OFF_XE;
  short* gi    = (short*)(ws + OFF_GI);
  float* last  = ws + OFF_LAST;
  float* vh    = ws + OFF_VH;

  k_prepvis<<<3392, 256, 0, stream>>>(Wself, Wmsg, mWih, vWih, wgt, age,
                                      fwW, fwB, faW, faB,
                                      cc, cp, cd, ec, ep, ed,
                                      w12t, wihb, wihTv, xe, vis, visb);
  k_mon <<<16384, 128, 0, stream>>>(cli, clv, cii, civ, eli, elv, eii, eiv,
                                    vis, monb, totb);
  k_gg  <<<512, 256, 0, stream>>>(monb, totb, visb, w12t, wihb, mbih, gi);
  k_mgru<<<128, 1024, 0, stream>>>(gi, mWhh, mbhh, last);
  k_vgru<<<160, 768, 0, stream>>>(last, xe, wihTv, vbih, vWhh, vbhh, vh);
  k_head<<<600, 256, 0, stream>>>(vh, Wp, bp, out);
}

// Round 2
// 280.218 us; speedup vs baseline: 1.0021x; 1.0021x over previous
//
#include <hip/hip_runtime.h>
#include <math.h>

#define B_   16
#define V_   16
#define C_   64
#define M_   32
#define CM_  16
#define D_   128
#define OUT_ 600
#define NSEQ 256      // B*V
#define NROW 8192     // B*V*M

typedef __attribute__((ext_vector_type(8))) short bf16x8;
typedef __attribute__((ext_vector_type(4))) short bf16x4;
typedef __attribute__((ext_vector_type(4))) float f32x4;

__device__ __forceinline__ unsigned short f2bf(float x) {
  union { float f; unsigned u; } v; v.f = x;
  unsigned r = v.u + 0x7fff + ((v.u >> 16) & 1);   // RNE
  return (unsigned short)(r >> 16);
}
__device__ __forceinline__ float bf2f(short s) {
  union { unsigned u; float f; } v;
  v.u = ((unsigned)(unsigned short)s) << 16;
  return v.f;
}
__device__ __forceinline__ float u2f(unsigned u) {
  union { unsigned u; float f; } v; v.u = u; return v.f;
}
// fast sigmoid / tanh: native v_exp + v_rcp (~5 inst), saturate correctly
__device__ __forceinline__ float fsig(float x)  { return __fdividef(1.f, 1.f + __expf(-x)); }
__device__ __forceinline__ float ftanh(float x) { return 1.f - 2.f*__fdividef(1.f, __expf(2.f*x) + 1.f); }

// LDS-only barrier: drains LDS ops for cross-wave visibility but does NOT
// drain vmcnt — in-flight global (gi prefetch) loads survive the barrier.
// __syncthreads() would emit s_waitcnt vmcnt(0) lgkmcnt(0) and serialize
// the per-step HBM prefetch latency into every GRU step.
__device__ __forceinline__ void ldsbar() {
  asm volatile("s_waitcnt lgkmcnt(0)" ::: "memory");
  __builtin_amdgcn_s_barrier();
  asm volatile("" ::: "memory");
}

// ---- workspace layout (float units; bf16 arrays are short* views) ----
constexpr int OFF_VIS   = 0;                               // fp32 [3][256][128]
constexpr int OFF_VISB  = 98304;                           // bf16 [3][256][128]
constexpr int OFF_MONB  = 147456;                          // bf16 [2][8192][128]
constexpr int OFF_TOTB  = 1196032;                         // bf16 [2][8192][128]
constexpr int OFF_W12T  = 2244608;                         // bf16 [8][128n][256k]
constexpr int OFF_WIHB  = 2375680;                         // bf16 [5][384n][128k]
constexpr int OFF_WIHTV = 2498560;                         // fp32 [4][128][384]
constexpr int OFF_XE    = 2695168;                         // fp32 [2][256][128]
constexpr int OFF_GI    = 2760704;                         // bf16 gi3[8][64][32][384][4]
constexpr int OFF_LAST  = 27926528;                        // fp32 [8][256][128]
constexpr int OFF_VH    = 29171712;                        // fp32 [10][16][128]

// =====================================================================
// prep+vis merged — verified, unchanged.
// =====================================================================
__global__ __launch_bounds__(256) void k_prepvis(
    const float* __restrict__ Wself, const float* __restrict__ Wmsg,
    const float* __restrict__ mWih,  const float* __restrict__ vWih,
    const float* __restrict__ wgt,   const float* __restrict__ age,
    const float* __restrict__ fwW,   const float* __restrict__ fwB,
    const float* __restrict__ faW,   const float* __restrict__ faB,
    const int* __restrict__ cc, const int* __restrict__ cp, const int* __restrict__ cd,
    const float* __restrict__ ec, const float* __restrict__ ep, const float* __restrict__ ed,
    short* __restrict__ w12t, short* __restrict__ wihb,
    float* __restrict__ wihTv, float* __restrict__ xe,
    float* __restrict__ vis, short* __restrict__ visb)
{
  int bx = blockIdx.x, tid = threadIdx.x;
  if (bx < 1024) {                      // w12t[pt][n][k] = bf16 combined
    int lin = bx*256 + tid;             // < 262144
    int pt = lin >> 15, rem = lin & 32767;
    int n = rem >> 8, k = rem & 255;
    float v;
    if (k < 128) v = Wself[pt*16384 + k*128 + n] - Wmsg[pt*16384 + k*128 + n]*(1.f/3.f);
    else         v = Wmsg[pt*16384 + (k-128)*128 + n]*(1.f/3.f);
    w12t[lin] = (short)f2bf(v);
  } else if (bx < 1984) {               // wihb = bf16(mWih) elementwise
    int lin = (bx-1024)*256 + tid;      // < 245760
    wihb[lin] = (short)f2bf(mWih[lin]);
  } else if (bx < 2752) {               // vgru Wih transpose fp32
    int lin = (bx-1984)*256 + tid;      // < 196608
    int g = lin / 49152, rem2 = lin % 49152;
    int k = rem2 / 384, j = rem2 % 384;
    wihTv[lin] = vWih[g*49152 + j*128 + k];
  } else if (bx < 3008) {               // xe for weight / age
    int lin = (bx-2752)*256 + tid;      // < 65536
    int which = lin >> 15, rem2 = lin & 32767;
    int n = rem2 >> 7, d = rem2 & 127;
    float x  = which ? age[n] : wgt[n];
    float Wv = which ? faW[d] : fwW[d];
    float bb = which ? faB[d] : fwB[d];
    xe[lin] = (x != 0.0f) ? (x*Wv + bb) : 0.0f;
  } else {                              // visit-event sum pools
    int idx = (bx-3008)*256 + tid;      // < 98304
    int type = idx >> 15;
    int r = idx & 32767;
    int bv = r >> 7, d = r & 127;
    const int*   codes = (type==0) ? cc : (type==1) ? cp : cd;
    const float* emb   = (type==0) ? ec : (type==1) ? ep : ed;
    float acc = 0.f;
    for (int c = 0; c < C_; ++c) {
      int code = codes[bv*C_ + c];
      acc += emb[code*D_ + d];
    }
    vis [(type*NSEQ + bv)*D_ + d] = acc;
    visb[(type*NSEQ + bv)*D_ + d] = (short)f2bf(acc);
  }
}

// =====================================================================
// monitor-event pools — unchanged (verified).
// =====================================================================
__global__ __launch_bounds__(128) void k_mon(
    const int* __restrict__ cli, const int* __restrict__ clv,
    const int* __restrict__ cii, const int* __restrict__ civ,
    const float* __restrict__ eli, const float* __restrict__ elv,
    const float* __restrict__ eii, const float* __restrict__ eiv,
    const float* __restrict__ vis,
    short* __restrict__ monb, short* __restrict__ totb)
{
  int p   = blockIdx.x >> 13;
  int bvm = blockIdx.x & 8191;
  int d   = threadIdx.x;
  const int* ci = p ? cii : cli;  const int* cv = p ? civ : clv;
  const float* ei = p ? eii : eli; const float* ev = p ? eiv : elv;
  float acc = 0.f;
  #pragma unroll
  for (int c = 0; c < CM_; ++c) {
    int iv = ci[bvm*CM_ + c];
    int vv = cv[bvm*CM_ + c];
    acc += ei[iv*D_ + d] * ev[vv*D_ + d];
  }
  int bv = bvm >> 5;
  float vsum = vis[bv*D_ + d] + vis[(NSEQ + bv)*D_ + d] + vis[(2*NSEQ + bv)*D_ + d];
  monb[(p*NROW + bvm)*D_ + d] = (short)f2bf(acc);
  totb[(p*NROW + bvm)*D_ + d] = (short)f2bf(acc + vsum);
}

// =====================================================================
// FUSED GNN+GI (MFMA bf16) — verified, unchanged.
// =====================================================================
__global__ __launch_bounds__(256, 4) void k_gg(
    const short* __restrict__ monb, const short* __restrict__ totb,
    const short* __restrict__ visb, const short* __restrict__ w12t,
    const short* __restrict__ wihb, const float* __restrict__ mbih,
    short* __restrict__ gi)
{
  const int pt = blockIdx.x >> 6;          // run 0..7
  const int rb = blockIdx.x & 63;
  const int p = pt >> 2, t = pt & 3;
  const int g = (pt % 4 == 0) ? (pt / 4) : (pt % 4 + 1);
  const int row0 = rb * 128;
  const int tid = threadIdx.x;
  const int w = tid >> 6, lane = tid & 63;
  const int c = lane & 15, q = lane >> 4;

  __shared__ short smem[2*128*72];         // 36864 B; Ys / giS alias
  short (*Xs)[72]  = (short(*)[72])smem;
  short (*Ws)[72]  = (short(*)[72])(smem + 128*72);
  short (*Ys)[136] = (short(*)[136])smem;
  float (*giS)[68] = (float(*)[68])smem;   // 128 x 68 fp32 = 34816 B

  const int rowL = tid >> 1, kc = tid & 1;
  const int rowG = row0 + rowL;
  const int bv = rowG >> 5;
  const int mg = w >> 1, ng = w & 1;

  f32x4 acc1[4][4];
  #pragma unroll
  for (int mi = 0; mi < 4; ++mi)
    #pragma unroll
    for (int ni = 0; ni < 4; ++ni) acc1[mi][ni] = (f32x4){0.f,0.f,0.f,0.f};

  const short* featp = (t == 0) ? (monb + ((size_t)p*NROW + rowG)*128)
                                : (visb + ((size_t)(t-1)*NSEQ + bv)*128);
  const short* totp  = totb + ((size_t)p*NROW + rowG)*128;
  const short* wrow  = w12t + ((size_t)pt*128 + rowL)*256;

  #pragma unroll 1
  for (int ks = 0; ks < 4; ++ks) {
    __syncthreads();
    int kg = ks*64 + kc*32;
    const short* srcX = (kg < 128) ? (featp + kg) : (totp + (kg - 128));
    const short* srcW = wrow + kg;
    short* dX = &Xs[rowL][kc*32];
    short* dW = &Ws[rowL][kc*32];
    #pragma unroll
    for (int i = 0; i < 4; ++i) {
      *(bf16x8*)(dX + 8*i) = *(const bf16x8*)(srcX + 8*i);
      *(bf16x8*)(dW + 8*i) = *(const bf16x8*)(srcW + 8*i);
    }
    __syncthreads();
    #pragma unroll
    for (int kk = 0; kk < 2; ++kk) {
      bf16x8 af[4], bfr[4];
      #pragma unroll
      for (int mi = 0; mi < 4; ++mi)
        af[mi] = *(const bf16x8*)&Xs[(mg*4+mi)*16 + c][kk*32 + q*8];
      #pragma unroll
      for (int ni = 0; ni < 4; ++ni)
        bfr[ni] = *(const bf16x8*)&Ws[(ng*4+ni)*16 + c][kk*32 + q*8];
      #pragma unroll
      for (int mi = 0; mi < 4; ++mi)
        #pragma unroll
        for (int ni = 0; ni < 4; ++ni)
          acc1[mi][ni] = __builtin_amdgcn_mfma_f32_16x16x32_bf16(af[mi], bfr[ni], acc1[mi][ni], 0, 0, 0);
    }
  }
  __syncthreads();     // done reading Xs/Ws (Ys aliases them)

  // relu + C-layout (col=lane&15, row=(lane>>4)*4+reg) -> Ys[row][col] bf16
  #pragma unroll
  for (int mi = 0; mi < 4; ++mi)
    #pragma unroll
    for (int ni = 0; ni < 4; ++ni)
      #pragma unroll
      for (int reg = 0; reg < 4; ++reg)
        Ys[(mg*4+mi)*16 + q*4 + reg][(ng*4+ni)*16 + c] =
            (short)f2bf(fmaxf(acc1[mi][ni][reg], 0.f));
  __syncthreads();

  // ---- stage 2: gi = Y @ Wih^T + bih ----
  bf16x8 Af[2][4];
  #pragma unroll
  for (int mi = 0; mi < 2; ++mi)
    #pragma unroll
    for (int kt = 0; kt < 4; ++kt)
      Af[mi][kt] = *(const bf16x8*)&Ys[(w*2+mi)*16 + c][kt*32 + q*8];

  float bihv[24];
  #pragma unroll
  for (int nt = 0; nt < 24; ++nt)
    bihv[nt] = mbih[g*384 + nt*16 + c];

  short* gslab = gi + (((size_t)pt*64 + rb)*32)*384*4;   // bf16 [m][col][s4]
  #pragma unroll 1
  for (int cn = 0; cn < 6; ++cn) {
    f32x4 acc2[2][4];
    #pragma unroll
    for (int mi = 0; mi < 2; ++mi)
      #pragma unroll
      for (int ni = 0; ni < 4; ++ni) acc2[mi][ni] = (f32x4){0.f,0.f,0.f,0.f};
    #pragma unroll
    for (int ni = 0; ni < 4; ++ni) {
      int n = (cn*4 + ni)*16 + c;
      const short* bp_ = wihb + ((size_t)g*384 + n)*128 + q*8;
      #pragma unroll
      for (int kt = 0; kt < 4; ++kt) {
        bf16x8 bfr = *(const bf16x8*)(bp_ + kt*32);
        #pragma unroll
        for (int mi = 0; mi < 2; ++mi)
          acc2[mi][ni] = __builtin_amdgcn_mfma_f32_16x16x32_bf16(Af[mi][kt], bfr, acc2[mi][ni], 0, 0, 0);
      }
    }
    __syncthreads();
    #pragma unroll
    for (int mi = 0; mi < 2; ++mi)
      #pragma unroll
      for (int ni = 0; ni < 4; ++ni) {
        float bia = bihv[cn*4+ni];
        #pragma unroll
        for (int reg = 0; reg < 4; ++reg)
          giS[(w*2+mi)*16 + q*4 + reg][ni*16 + c] = acc2[mi][ni][reg] + bia;
      }
    __syncthreads();
    #pragma unroll
    for (int k = 0; k < 8; ++k) {
      int o4 = tid + k*256;            // 0..2047
      int m = o4 >> 6, colL = o4 & 63;
      bf16x4 v;
      v[0] = (short)f2bf(giS[m][colL]);
      v[1] = (short)f2bf(giS[32+m][colL]);
      v[2] = (short)f2bf(giS[64+m][colL]);
      v[3] = (short)f2bf(giS[96+m][colL]);
      *(bf16x4*)&gslab[((size_t)m*384 + cn*64 + colL)*4] = v;
    }
  }
}

// =====================================================================
// monitor-level GRU v7.1 — THIS ROUND: in-loop barriers changed from
// __syncthreads() (which drains vmcnt(0), serializing the per-step gi
// HBM prefetch latency into every step) to ldsbar() = lgkmcnt(0)-only +
// raw s_barrier. gi prefetch loads now stay in flight across barriers;
// the compiler's dependency-tracked vmcnt(N) before the USE (next step)
// is the only wait. Structure otherwise identical to round-0 v7.
// =====================================================================
__global__ __launch_bounds__(1024) void k_mgru(
    const short* __restrict__ gi, const float* __restrict__ mWhh,
    const float* __restrict__ mbhh, float* __restrict__ last)
{
  const int run  = blockIdx.x >> 4;     // 0..7
  const int pair = blockIdx.x & 15;     // 0..15 == batch index b (16 seq = 16 visits)
  const int g = (run % 4 == 0) ? (run / 4) : (run % 4 + 1);
  const int tid = threadIdx.x;
  const int w = tid >> 6;               // wave 0..15
  const int lane = tid & 63;
  const int c = lane & 15, q = lane >> 4;

  __shared__ short hb[2][4][16][40];    // [buf][kt][seq][kk] bf16, 10240 B
  __shared__ float gS[384][20];         // [gate-col][seq(16)+pad4] fp32, 30720 B

  for (int idx = tid; idx < 2*4*16*40; idx += 1024)
    ((short*)hb)[idx] = 0;

  // ---- MFMA waves: w 0..11; wave covers cols [gate*128 + nt*32, +32) ----
  const bool mfw = (w < 12);
  const int gate_w = w >> 2;            // 0..2
  const int nt = w & 3;                 // 0..3
  bf16x8 bfrag[2][4];
  if (mfw) {
    #pragma unroll
    for (int ti = 0; ti < 2; ++ti) {
      const int col = gate_w*128 + nt*32 + ti*16 + c;
      const float* wp = mWhh + ((size_t)g*384 + col)*128 + q*8;
      #pragma unroll
      for (int kt = 0; kt < 4; ++kt) {
        float4 lo = *(const float4*)(wp + kt*32);
        float4 hi = *(const float4*)(wp + kt*32 + 4);
        bf16x8 tt;
        tt[0]=(short)f2bf(lo.x); tt[1]=(short)f2bf(lo.y); tt[2]=(short)f2bf(lo.z); tt[3]=(short)f2bf(lo.w);
        tt[4]=(short)f2bf(hi.x); tt[5]=(short)f2bf(hi.y); tt[6]=(short)f2bf(hi.z); tt[7]=(short)f2bf(hi.w);
        bfrag[ti][kt] = tt;
      }
    }
  }

  // ---- activation mapping: lane owns hidden j for seqs (s0, s0+1) ----
  const int j  = tid >> 3;              // 0..127
  const int sp = tid & 7;               // 0..7
  const int s0 = sp*2;                  // even seq
  const int ktj = j >> 5, kkj = j & 31;
  const float bh0 = mbhh[g*384 +       j];
  const float bh1 = mbhh[g*384 + 128 + j];
  const float bh2 = mbhh[g*384 + 256 + j];
  // gi (bf16) element: idx = (((run*64 + pair*4 + quad)*32 + m)*384 + gate*128 + j)*4 + (s&3)
  const short* gip = gi + (((size_t)run*64 + pair*4 + (s0>>2))*32)*384*4
                        + (size_t)j*4 + (s0&3);
  // per-load add: gate*512 (shorts) ; per-step add: m*1536 (shorts)

  float h0 = 0.f, h1 = 0.f;

  unsigned gA[3], gB[3];
  #pragma unroll
  for (int gate = 0; gate < 3; ++gate)
    gA[gate] = *(const unsigned*)(gip + gate*512);
  __syncthreads();

  auto step = [&](int m, unsigned (&gcur)[3], unsigned (&gnext)[3]) {
    const int cur = m & 1, nxt = cur ^ 1;
    if (mfw) {
      bf16x8 a[4];
      #pragma unroll
      for (int kt = 0; kt < 4; ++kt)
        a[kt] = *(const bf16x8*)&hb[cur][kt][c][q*8];   // A[seq=c][k]
      #pragma unroll
      for (int ti = 0; ti < 2; ++ti) {
        f32x4 acc = (f32x4){0.f,0.f,0.f,0.f};
        #pragma unroll
        for (int kt = 0; kt < 4; ++kt)
          acc = __builtin_amdgcn_mfma_f32_16x16x32_bf16(a[kt], bfrag[ti][kt], acc, 0, 0, 0);
        const int col = gate_w*128 + nt*32 + ti*16 + c;
        *(f32x4*)&gS[col][q*4] = acc;                    // rows seq q*4..q*4+3
      }
    }
    ldsbar();   // gS(m) ready; guards gS reuse; gi prefetch stays in flight

    // ---- activation: all 1024 lanes, 2 items each ----
    float2 vr = *(const float2*)&gS[      j][s0];
    float2 vz = *(const float2*)&gS[128 + j][s0];
    float2 vn = *(const float2*)&gS[256 + j][s0];
    if (m < 31) {
      const short* gp = gip + (size_t)(m+1)*1536;
      #pragma unroll
      for (int gate = 0; gate < 3; ++gate)
        gnext[gate] = *(const unsigned*)(gp + gate*512);
    }
    float gi0a = u2f(gcur[0] << 16), gi0b = u2f(gcur[0] & 0xffff0000u);
    float gi1a = u2f(gcur[1] << 16), gi1b = u2f(gcur[1] & 0xffff0000u);
    float gi2a = u2f(gcur[2] << 16), gi2b = u2f(gcur[2] & 0xffff0000u);

    float r0 = fsig(vr.x + bh0 + gi0a);
    float z0 = fsig(vz.x + bh1 + gi1a);
    float n0 = ftanh(gi2a + r0*(vn.x + bh2));
    h0 = (1.f - z0)*n0 + z0*h0;
    float r1 = fsig(vr.y + bh0 + gi0b);
    float z1 = fsig(vz.y + bh1 + gi1b);
    float n1 = ftanh(gi2b + r1*(vn.y + bh2));
    h1 = (1.f - z1)*n1 + z1*h1;

    hb[nxt][ktj][s0    ][kkj] = (short)f2bf(h0);
    hb[nxt][ktj][s0 + 1][kkj] = (short)f2bf(h1);
    ldsbar();   // hb(nxt) visible for step m+1's MFMA reads
  };

  #pragma unroll 1
  for (int m2 = 0; m2 < 16; ++m2) {
    step(2*m2,     gA, gB);
    step(2*m2 + 1, gB, gA);
  }

  last[((size_t)run*NSEQ + pair*16 + s0    )*D_ + j] = h0;
  last[((size_t)run*NSEQ + pair*16 + s0 + 1)*D_ + j] = h1;
}

// =====================================================================
// visit-level GRU v3 (vgi fused) — verified, unchanged.
// =====================================================================
__global__ __launch_bounds__(768) void k_vgru(
    const float* __restrict__ last, const float* __restrict__ xe,
    const float* __restrict__ wihTv, const float* __restrict__ vbih,
    const float* __restrict__ vWhh, const float* __restrict__ vbhh,
    float* __restrict__ vh)
{
  int run = blockIdx.x >> 4, b = blockIdx.x & 15;
  int tid = threadIdx.x;
  int vidx = (run < 4) ? 0 : (run < 8) ? 1 : (run - 6);

  __shared__ float Xs[16][128];          // 8 KB
  __shared__ float giL[16*384];          // 24 KB
  __shared__ __align__(16) float hsv[128];
  __shared__ float gh[384];

  const float* X = (run < 8) ? (last + ((size_t)run*NSEQ + b*16)*D_)
                             : (xe + ((size_t)(run-8)*NSEQ + b*16)*D_);
  for (int idx = tid; idx < 2048; idx += 768)
    ((float*)Xs)[idx] = X[idx];
  if (tid < 128) hsv[tid] = 0.f;
  __syncthreads();

  // ---- gi precompute into LDS: thread (half, j) does 8 visits ----
  {
    int half = (tid >= 384) ? 1 : 0;
    int j = tid - half*384;
    float accv[8];
    float bias = vbih[vidx*384 + j];
    #pragma unroll
    for (int s = 0; s < 8; ++s) accv[s] = bias;
    const float* W = wihTv + vidx*49152 + j;
    #pragma unroll 4
    for (int k = 0; k < 128; ++k) {
      float wv = W[k*384];
      #pragma unroll
      for (int s = 0; s < 8; ++s) accv[s] += Xs[half*8 + s][k] * wv;
    }
    #pragma unroll
    for (int s = 0; s < 8; ++s)
      giL[(half*8 + s)*384 + j] = accv[s];
  }

  // ---- recurrence weights (pair-split, w[64]/thread, no spill) ----
  int j = tid >> 1, kh = tid & 1;
  float w[64];
  const float4* wrow = (const float4*)(vWhh + (vidx*384 + j)*128 + kh*64);
  #pragma unroll
  for (int k4 = 0; k4 < 16; ++k4) {
    float4 t4 = wrow[k4];
    w[4*k4] = t4.x; w[4*k4+1] = t4.y; w[4*k4+2] = t4.z; w[4*k4+3] = t4.w;
  }
  float bj = vbhh[vidx*384 + j];
  __syncthreads();

  #pragma unroll 1
  for (int v = 0; v < 16; ++v) {
    const float4* h4 = (const float4*)(hsv + kh*64);
    float p0 = 0.f, p1 = 0.f;
    #pragma unroll
    for (int k4 = 0; k4 < 8; ++k4) {
      float4 u0 = h4[k4], u1 = h4[k4+8];
      p0 += w[4*k4   ]*u0.x + w[4*k4+1 ]*u0.y + w[4*k4+2 ]*u0.z + w[4*k4+3 ]*u0.w;
      p1 += w[4*k4+32]*u1.x + w[4*k4+33]*u1.y + w[4*k4+34]*u1.z + w[4*k4+35]*u1.w;
    }
    float part = p0 + p1;
    part += __shfl_xor(part, 1);
    if (kh == 0) gh[j] = bj + ((j < 256) ? giL[v*384 + j] : 0.f) + part;
    __syncthreads();
    if (tid < 128) {
      float r = fsig(gh[tid]);
      float z = fsig(gh[tid+128]);
      float gin = giL[v*384 + 256 + tid];
      float n = ftanh(gin + r*gh[tid+256]);
      hsv[tid] = (1.f - z)*n + z*hsv[tid];
    }
    __syncthreads();
  }
  if (tid < 128) vh[(run*16 + b)*D_ + tid] = hsv[tid];
}

// =====================================================================
// head v4 (pe fused) — verified, unchanged.
// =====================================================================
__global__ __launch_bounds__(256) void k_head(
    const float* __restrict__ vh, const float* __restrict__ Wp,
    const float* __restrict__ bp, float* __restrict__ out)
{
  const int o = blockIdx.x;
  const int tid = threadIdx.x;
  const int b = tid & 15, kc = tid >> 4;
  const int a1[7] = {0,1,2,3,4,8,9};
  const int a2[7] = {-1,5,6,7,-1,-1,-1};
  const float4* wb = (const float4*)(Wp + (size_t)o*896 + kc*56);
  float acc = 0.f;
  #pragma unroll
  for (int i = 0; i < 14; ++i) {
    int cc2 = kc*56 + i*4;
    int s = cc2 >> 7, d0 = cc2 & 127;
    float4 a = *(const float4*)(vh + (a1[s]*16 + b)*D_ + d0);
    int s2 = a2[s];
    if (s2 >= 0) {
      float4 a2v = *(const float4*)(vh + (s2*16 + b)*D_ + d0);
      a.x += a2v.x; a.y += a2v.y; a.z += a2v.z; a.w += a2v.w;
    }
    a.x = fmaxf(a.x, 0.f); a.y = fmaxf(a.y, 0.f);
    a.z = fmaxf(a.z, 0.f); a.w = fmaxf(a.w, 0.f);
    float4 ww = wb[i];
    acc += a.x*ww.x + a.y*ww.y + a.z*ww.z + a.w*ww.w;
  }
  __shared__ float red[16][17];
  red[kc][b] = acc;
  __syncthreads();
  if (tid < 16) {
    float s = 0.f;
    #pragma unroll
    for (int k = 0; k < 16; ++k) s += red[k][tid];
    out[tid*OUT_ + o] = s + bp[o];
  }
}

// =====================================================================
extern "C" void kernel_launch(void* const* d_in, const int* in_sizes, int n_in,
                              void* d_out, int out_size, void* d_ws, size_t ws_size,
                              hipStream_t stream)
{
  (void)in_sizes; (void)n_in; (void)out_size; (void)ws_size;
  const int*   cc   = (const int*)  d_in[0];
  const int*   cp   = (const int*)  d_in[1];
  const int*   cd   = (const int*)  d_in[2];
  const int*   cli  = (const int*)  d_in[3];
  const int*   clv  = (const int*)  d_in[4];
  const int*   cii  = (const int*)  d_in[5];
  const int*   civ  = (const int*)  d_in[6];
  const float* wgt  = (const float*)d_in[7];
  const float* age  = (const float*)d_in[8];
  const float* ec   = (const float*)d_in[9];
  const float* ep   = (const float*)d_in[10];
  const float* ed   = (const float*)d_in[11];
  const float* eli  = (const float*)d_in[12];
  const float* elv  = (const float*)d_in[13];
  const float* eii  = (const float*)d_in[14];
  const float* eiv  = (const float*)d_in[15];
  const float* mWih = (const float*)d_in[16];
  const float* mWhh = (const float*)d_in[17];
  const float* mbih = (const float*)d_in[18];
  const float* mbhh = (const float*)d_in[19];
  const float* vWih = (const float*)d_in[20];
  const float* vWhh = (const float*)d_in[21];
  const float* vbih = (const float*)d_in[22];
  const float* vbhh = (const float*)d_in[23];
  const float* Wself= (const float*)d_in[24];
  const float* Wmsg = (const float*)d_in[25];
  const float* fwW  = (const float*)d_in[26];
  const float* fwB  = (const float*)d_in[27];
  const float* faW  = (const float*)d_in[28];
  const float* faB  = (const float*)d_in[29];
  const float* Wp   = (const float*)d_in[30];
  const float* bp   = (const float*)d_in[31];
  float* out = (float*)d_out;
  float* ws  = (float*)d_ws;

  float* vis   = ws + OFF_VIS;
  short* visb  = (short*)(ws + OFF_VISB);
  short* monb  = (short*)(ws + OFF_MONB);
  short* totb  = (short*)(ws + OFF_TOTB);
  short* w12t  = (short*)(ws + OFF_W12T);
  short* wihb  = (short*)(ws + OFF_WIHB);
  float* wihTv = ws + OFF_WIHTV;
  float* xe    = ws + OFF_XE;
  short* gi    = (short*)(ws + OFF_GI);
  float* last  = ws + OFF_LAST;
  float* vh    = ws + OFF_VH;

  k_prepvis<<<3392, 256, 0, stream>>>(Wself, Wmsg, mWih, vWih, wgt, age,
                                      fwW, fwB, faW, faB,
                                      cc, cp, cd, ec, ep, ed,
                                      w12t, wihb, wihTv, xe, vis, visb);
  k_mon <<<16384, 128, 0, stream>>>(cli, clv, cii, civ, eli, elv, eii, eiv,
                                    vis, monb, totb);
  k_gg  <<<512, 256, 0, stream>>>(monb, totb, visb, w12t, wihb, mbih, gi);
  k_mgru<<<128, 1024, 0, stream>>>(gi, mWhh, mbhh, last);
  k_vgru<<<160, 768, 0, stream>>>(last, xe, wihTv, vbih, vWhh, vbhh, vh);
  k_head<<<600, 256, 0, stream>>>(vh, Wp, bp, out);
}

// Round 3
// 268.670 us; speedup vs baseline: 1.0452x; 1.0430x over previous
//
#include <hip/hip_runtime.h>
#include <math.h>

#define B_   16
#define V_   16
#define C_   64
#define M_   32
#define CM_  16
#define D_   128
#define OUT_ 600
#define NSEQ 256      // B*V
#define NROW 8192     // B*V*M

typedef __attribute__((ext_vector_type(8))) short bf16x8;
typedef __attribute__((ext_vector_type(4))) short bf16x4;
typedef __attribute__((ext_vector_type(4))) float f32x4;

__device__ __forceinline__ unsigned short f2bf(float x) {
  union { float f; unsigned u; } v; v.f = x;
  unsigned r = v.u + 0x7fff + ((v.u >> 16) & 1);   // RNE
  return (unsigned short)(r >> 16);
}
__device__ __forceinline__ float bf2f(short s) {
  union { unsigned u; float f; } v;
  v.u = ((unsigned)(unsigned short)s) << 16;
  return v.f;
}
__device__ __forceinline__ float u2f(unsigned u) {
  union { unsigned u; float f; } v; v.u = u; return v.f;
}
// fast sigmoid / tanh: native v_exp + v_rcp (~5 inst), saturate correctly
__device__ __forceinline__ float fsig(float x)  { return __fdividef(1.f, 1.f + __expf(-x)); }
__device__ __forceinline__ float ftanh(float x) { return 1.f - 2.f*__fdividef(1.f, __expf(2.f*x) + 1.f); }

// LDS-only barrier: drains LDS ops for cross-wave visibility but does NOT
// drain vmcnt — in-flight global (gi prefetch) loads survive the barrier.
__device__ __forceinline__ void ldsbar() {
  asm volatile("s_waitcnt lgkmcnt(0)" ::: "memory");
  __builtin_amdgcn_s_barrier();
  asm volatile("" ::: "memory");
}

// ---- workspace layout (float units; bf16 arrays are short* views) ----
constexpr int OFF_VIS   = 0;                               // fp32 [3][256][128]
constexpr int OFF_VISB  = 98304;                           // bf16 [3][256][128]
constexpr int OFF_MONB  = 147456;                          // bf16 [2][8192][128]
constexpr int OFF_TOTB  = 1196032;                         // bf16 [2][8192][128]
constexpr int OFF_W12T  = 2244608;                         // bf16 [8][128n][256k]
constexpr int OFF_WIHB  = 2375680;                         // bf16 [5][384n][128k]
constexpr int OFF_WIHTV = 2498560;                         // fp32 [4][128][384]
constexpr int OFF_XE    = 2695168;                         // fp32 [2][256][128]
constexpr int OFF_GI    = 2760704;                         // bf16 gi3[8][64][32][384][4]
constexpr int OFF_LAST  = 27926528;                        // fp32 [8][256][128]
constexpr int OFF_VH    = 29171712;                        // fp32 [10][16][128]

// =====================================================================
// prep+vis merged — verified, unchanged.
// =====================================================================
__global__ __launch_bounds__(256) void k_prepvis(
    const float* __restrict__ Wself, const float* __restrict__ Wmsg,
    const float* __restrict__ mWih,  const float* __restrict__ vWih,
    const float* __restrict__ wgt,   const float* __restrict__ age,
    const float* __restrict__ fwW,   const float* __restrict__ fwB,
    const float* __restrict__ faW,   const float* __restrict__ faB,
    const int* __restrict__ cc, const int* __restrict__ cp, const int* __restrict__ cd,
    const float* __restrict__ ec, const float* __restrict__ ep, const float* __restrict__ ed,
    short* __restrict__ w12t, short* __restrict__ wihb,
    float* __restrict__ wihTv, float* __restrict__ xe,
    float* __restrict__ vis, short* __restrict__ visb)
{
  int bx = blockIdx.x, tid = threadIdx.x;
  if (bx < 1024) {                      // w12t[pt][n][k] = bf16 combined
    int lin = bx*256 + tid;             // < 262144
    int pt = lin >> 15, rem = lin & 32767;
    int n = rem >> 8, k = rem & 255;
    float v;
    if (k < 128) v = Wself[pt*16384 + k*128 + n] - Wmsg[pt*16384 + k*128 + n]*(1.f/3.f);
    else         v = Wmsg[pt*16384 + (k-128)*128 + n]*(1.f/3.f);
    w12t[lin] = (short)f2bf(v);
  } else if (bx < 1984) {               // wihb = bf16(mWih) elementwise
    int lin = (bx-1024)*256 + tid;      // < 245760
    wihb[lin] = (short)f2bf(mWih[lin]);
  } else if (bx < 2752) {               // vgru Wih transpose fp32
    int lin = (bx-1984)*256 + tid;      // < 196608
    int g = lin / 49152, rem2 = lin % 49152;
    int k = rem2 / 384, j = rem2 % 384;
    wihTv[lin] = vWih[g*49152 + j*128 + k];
  } else if (bx < 3008) {               // xe for weight / age
    int lin = (bx-2752)*256 + tid;      // < 65536
    int which = lin >> 15, rem2 = lin & 32767;
    int n = rem2 >> 7, d = rem2 & 127;
    float x  = which ? age[n] : wgt[n];
    float Wv = which ? faW[d] : fwW[d];
    float bb = which ? faB[d] : fwB[d];
    xe[lin] = (x != 0.0f) ? (x*Wv + bb) : 0.0f;
  } else {                              // visit-event sum pools
    int idx = (bx-3008)*256 + tid;      // < 98304
    int type = idx >> 15;
    int r = idx & 32767;
    int bv = r >> 7, d = r & 127;
    const int*   codes = (type==0) ? cc : (type==1) ? cp : cd;
    const float* emb   = (type==0) ? ec : (type==1) ? ep : ed;
    float acc = 0.f;
    for (int c = 0; c < C_; ++c) {
      int code = codes[bv*C_ + c];
      acc += emb[code*D_ + d];
    }
    vis [(type*NSEQ + bv)*D_ + d] = acc;
    visb[(type*NSEQ + bv)*D_ + d] = (short)f2bf(acc);
  }
}

// =====================================================================
// monitor-event pools — unchanged (verified).
// =====================================================================
__global__ __launch_bounds__(128) void k_mon(
    const int* __restrict__ cli, const int* __restrict__ clv,
    const int* __restrict__ cii, const int* __restrict__ civ,
    const float* __restrict__ eli, const float* __restrict__ elv,
    const float* __restrict__ eii, const float* __restrict__ eiv,
    const float* __restrict__ vis,
    short* __restrict__ monb, short* __restrict__ totb)
{
  int p   = blockIdx.x >> 13;
  int bvm = blockIdx.x & 8191;
  int d   = threadIdx.x;
  const int* ci = p ? cii : cli;  const int* cv = p ? civ : clv;
  const float* ei = p ? eii : eli; const float* ev = p ? eiv : elv;
  float acc = 0.f;
  #pragma unroll
  for (int c = 0; c < CM_; ++c) {
    int iv = ci[bvm*CM_ + c];
    int vv = cv[bvm*CM_ + c];
    acc += ei[iv*D_ + d] * ev[vv*D_ + d];
  }
  int bv = bvm >> 5;
  float vsum = vis[bv*D_ + d] + vis[(NSEQ + bv)*D_ + d] + vis[(2*NSEQ + bv)*D_ + d];
  monb[(p*NROW + bvm)*D_ + d] = (short)f2bf(acc);
  totb[(p*NROW + bvm)*D_ + d] = (short)f2bf(acc + vsum);
}

// =====================================================================
// FUSED GNN+GI (MFMA bf16) — verified, unchanged.
// =====================================================================
__global__ __launch_bounds__(256, 4) void k_gg(
    const short* __restrict__ monb, const short* __restrict__ totb,
    const short* __restrict__ visb, const short* __restrict__ w12t,
    const short* __restrict__ wihb, const float* __restrict__ mbih,
    short* __restrict__ gi)
{
  const int pt = blockIdx.x >> 6;          // run 0..7
  const int rb = blockIdx.x & 63;
  const int p = pt >> 2, t = pt & 3;
  const int g = (pt % 4 == 0) ? (pt / 4) : (pt % 4 + 1);
  const int row0 = rb * 128;
  const int tid = threadIdx.x;
  const int w = tid >> 6, lane = tid & 63;
  const int c = lane & 15, q = lane >> 4;

  __shared__ short smem[2*128*72];         // 36864 B; Ys / giS alias
  short (*Xs)[72]  = (short(*)[72])smem;
  short (*Ws)[72]  = (short(*)[72])(smem + 128*72);
  short (*Ys)[136] = (short(*)[136])smem;
  float (*giS)[68] = (float(*)[68])smem;   // 128 x 68 fp32 = 34816 B

  const int rowL = tid >> 1, kc = tid & 1;
  const int rowG = row0 + rowL;
  const int bv = rowG >> 5;
  const int mg = w >> 1, ng = w & 1;

  f32x4 acc1[4][4];
  #pragma unroll
  for (int mi = 0; mi < 4; ++mi)
    #pragma unroll
    for (int ni = 0; ni < 4; ++ni) acc1[mi][ni] = (f32x4){0.f,0.f,0.f,0.f};

  const short* featp = (t == 0) ? (monb + ((size_t)p*NROW + rowG)*128)
                                : (visb + ((size_t)(t-1)*NSEQ + bv)*128);
  const short* totp  = totb + ((size_t)p*NROW + rowG)*128;
  const short* wrow  = w12t + ((size_t)pt*128 + rowL)*256;

  #pragma unroll 1
  for (int ks = 0; ks < 4; ++ks) {
    __syncthreads();
    int kg = ks*64 + kc*32;
    const short* srcX = (kg < 128) ? (featp + kg) : (totp + (kg - 128));
    const short* srcW = wrow + kg;
    short* dX = &Xs[rowL][kc*32];
    short* dW = &Ws[rowL][kc*32];
    #pragma unroll
    for (int i = 0; i < 4; ++i) {
      *(bf16x8*)(dX + 8*i) = *(const bf16x8*)(srcX + 8*i);
      *(bf16x8*)(dW + 8*i) = *(const bf16x8*)(srcW + 8*i);
    }
    __syncthreads();
    #pragma unroll
    for (int kk = 0; kk < 2; ++kk) {
      bf16x8 af[4], bfr[4];
      #pragma unroll
      for (int mi = 0; mi < 4; ++mi)
        af[mi] = *(const bf16x8*)&Xs[(mg*4+mi)*16 + c][kk*32 + q*8];
      #pragma unroll
      for (int ni = 0; ni < 4; ++ni)
        bfr[ni] = *(const bf16x8*)&Ws[(ng*4+ni)*16 + c][kk*32 + q*8];
      #pragma unroll
      for (int mi = 0; mi < 4; ++mi)
        #pragma unroll
        for (int ni = 0; ni < 4; ++ni)
          acc1[mi][ni] = __builtin_amdgcn_mfma_f32_16x16x32_bf16(af[mi], bfr[ni], acc1[mi][ni], 0, 0, 0);
    }
  }
  __syncthreads();     // done reading Xs/Ws (Ys aliases them)

  // relu + C-layout (col=lane&15, row=(lane>>4)*4+reg) -> Ys[row][col] bf16
  #pragma unroll
  for (int mi = 0; mi < 4; ++mi)
    #pragma unroll
    for (int ni = 0; ni < 4; ++ni)
      #pragma unroll
      for (int reg = 0; reg < 4; ++reg)
        Ys[(mg*4+mi)*16 + q*4 + reg][(ng*4+ni)*16 + c] =
            (short)f2bf(fmaxf(acc1[mi][ni][reg], 0.f));
  __syncthreads();

  // ---- stage 2: gi = Y @ Wih^T + bih ----
  bf16x8 Af[2][4];
  #pragma unroll
  for (int mi = 0; mi < 2; ++mi)
    #pragma unroll
    for (int kt = 0; kt < 4; ++kt)
      Af[mi][kt] = *(const bf16x8*)&Ys[(w*2+mi)*16 + c][kt*32 + q*8];

  float bihv[24];
  #pragma unroll
  for (int nt = 0; nt < 24; ++nt)
    bihv[nt] = mbih[g*384 + nt*16 + c];

  short* gslab = gi + (((size_t)pt*64 + rb)*32)*384*4;   // bf16 [m][col][s4]
  #pragma unroll 1
  for (int cn = 0; cn < 6; ++cn) {
    f32x4 acc2[2][4];
    #pragma unroll
    for (int mi = 0; mi < 2; ++mi)
      #pragma unroll
      for (int ni = 0; ni < 4; ++ni) acc2[mi][ni] = (f32x4){0.f,0.f,0.f,0.f};
    #pragma unroll
    for (int ni = 0; ni < 4; ++ni) {
      int n = (cn*4 + ni)*16 + c;
      const short* bp_ = wihb + ((size_t)g*384 + n)*128 + q*8;
      #pragma unroll
      for (int kt = 0; kt < 4; ++kt) {
        bf16x8 bfr = *(const bf16x8*)(bp_ + kt*32);
        #pragma unroll
        for (int mi = 0; mi < 2; ++mi)
          acc2[mi][ni] = __builtin_amdgcn_mfma_f32_16x16x32_bf16(Af[mi][kt], bfr, acc2[mi][ni], 0, 0, 0);
      }
    }
    __syncthreads();
    #pragma unroll
    for (int mi = 0; mi < 2; ++mi)
      #pragma unroll
      for (int ni = 0; ni < 4; ++ni) {
        float bia = bihv[cn*4+ni];
        #pragma unroll
        for (int reg = 0; reg < 4; ++reg)
          giS[(w*2+mi)*16 + q*4 + reg][ni*16 + c] = acc2[mi][ni][reg] + bia;
      }
    __syncthreads();
    #pragma unroll
    for (int k = 0; k < 8; ++k) {
      int o4 = tid + k*256;            // 0..2047
      int m = o4 >> 6, colL = o4 & 63;
      bf16x4 v;
      v[0] = (short)f2bf(giS[m][colL]);
      v[1] = (short)f2bf(giS[32+m][colL]);
      v[2] = (short)f2bf(giS[64+m][colL]);
      v[3] = (short)f2bf(giS[96+m][colL]);
      *(bf16x4*)&gslab[((size_t)m*384 + cn*64 + colL)*4] = v;
    }
  }
}

// =====================================================================
// monitor-level GRU v8 — THIS ROUND: gate-slice-per-wave, lane-local
// activation, ONE barrier + ONE LDS round-trip per step.
// Key: for gate cols j, 128+j, 256+j the (seq,j) element lands in the
// SAME lane & reg of the 3 accumulators (C layout depends on col&15
// only) -> activation needs no LDS relay, no gS, no second barrier.
// 128 blocks x 512 thr (8 waves = 8 hidden-j slices of 16).
// Per wave per step: 4 ds_read_b128 (h frags) + 12 MFMA + 3x8B gi loads
// (prefetched 1 step ahead) + 4 lane-local GRU items + 4 ds_write_b16.
// =====================================================================
__global__ __launch_bounds__(512, 2) void k_mgru(
    const short* __restrict__ gi, const float* __restrict__ mWhh,
    const float* __restrict__ mbhh, float* __restrict__ last)
{
  const int run  = blockIdx.x >> 4;     // 0..7
  const int pair = blockIdx.x & 15;     // 0..15 (16 seqs per block)
  const int g = (run % 4 == 0) ? (run / 4) : (run % 4 + 1);
  const int tid = threadIdx.x;
  const int w = tid >> 6;               // wave 0..7 = hidden slice
  const int lane = tid & 63;
  const int c = lane & 15, q = lane >> 4;
  const int j = w*16 + c;               // hidden index 0..127

  __shared__ short hb[2][4][16][40];    // [buf][kt][seq][kk+pad] bf16, 10240 B

  for (int idx = tid; idx < 2*4*16*40; idx += 512)
    ((short*)hb)[idx] = 0;

  // ---- B fragments in registers: Whh rows for cols gate*128+j ----
  bf16x8 bfrag[3][4];
  #pragma unroll
  for (int gate = 0; gate < 3; ++gate) {
    const float* wp = mWhh + ((size_t)g*384 + gate*128 + j)*128 + q*8;
    #pragma unroll
    for (int kt = 0; kt < 4; ++kt) {
      float4 lo = *(const float4*)(wp + kt*32);
      float4 hi = *(const float4*)(wp + kt*32 + 4);
      bf16x8 t;
      t[0]=(short)f2bf(lo.x); t[1]=(short)f2bf(lo.y); t[2]=(short)f2bf(lo.z); t[3]=(short)f2bf(lo.w);
      t[4]=(short)f2bf(hi.x); t[5]=(short)f2bf(hi.y); t[6]=(short)f2bf(hi.z); t[7]=(short)f2bf(hi.w);
      bfrag[gate][kt] = t;
    }
  }
  const float bh0 = mbhh[g*384 +       j];
  const float bh1 = mbhh[g*384 + 128 + j];
  const float bh2 = mbhh[g*384 + 256 + j];

  // gi slab for this lane's seq-quad q: element (m, col, s&3)
  // shorts index: ((run*64 + pair*4 + q)*32 + m)*1536 + col*4 + (s&3)
  const short* gib = gi + ((size_t)((run*64 + pair*4 + q)*32))*1536;

  float hf[4] = {0.f,0.f,0.f,0.f};
  const int ktw = w >> 1;               // j>>5
  const int kkw = (w & 1)*16 + c;       // j&31

  bf16x4 gA[3], gB[3];
  #pragma unroll
  for (int gate = 0; gate < 3; ++gate)
    gA[gate] = *(const bf16x4*)&gib[(size_t)(gate*128 + j)*4];
  __syncthreads();

  auto step = [&](int m, bf16x4 (&gcur)[3], bf16x4 (&gnext)[3]) {
    const int cur = m & 1, nxt = cur ^ 1;
    // h(m-1) fragments: A[row=seq=c][k = kt*32 + q*8 + i]
    bf16x8 a[4];
    #pragma unroll
    for (int kt = 0; kt < 4; ++kt)
      a[kt] = *(const bf16x8*)&hb[cur][kt][c][q*8];
    // 3 gates x K=128 for this wave's 16 cols
    f32x4 acc[3];
    #pragma unroll
    for (int gate = 0; gate < 3; ++gate) {
      f32x4 t = {0.f,0.f,0.f,0.f};
      #pragma unroll
      for (int kt = 0; kt < 4; ++kt)
        t = __builtin_amdgcn_mfma_f32_16x16x32_bf16(a[kt], bfrag[gate][kt], t, 0, 0, 0);
      acc[gate] = t;
    }
    // prefetch next step's gi (stays in flight across ldsbar)
    if (m < 31) {
      const short* gp = gib + (size_t)(m+1)*1536;
      #pragma unroll
      for (int gate = 0; gate < 3; ++gate)
        gnext[gate] = *(const bf16x4*)&gp[(size_t)(gate*128 + j)*4];
    }
    // lane-local GRU activation: (seq = q*4+reg, this j)
    #pragma unroll
    for (int reg = 0; reg < 4; ++reg) {
      float g0 = bf2f(gcur[0][reg]);
      float g1 = bf2f(gcur[1][reg]);
      float g2 = bf2f(gcur[2][reg]);
      float rr = fsig(acc[0][reg] + bh0 + g0);
      float zz = fsig(acc[1][reg] + bh1 + g1);
      float nn = ftanh(g2 + rr*(acc[2][reg] + bh2));
      float hnew = (1.f - zz)*nn + zz*hf[reg];
      hf[reg] = hnew;
      hb[nxt][ktw][q*4 + reg][kkw] = (short)f2bf(hnew);
    }
    ldsbar();   // h(m) visible for step m+1; gi loads stay in flight
  };

  #pragma unroll 1
  for (int m2 = 0; m2 < 16; ++m2) {
    step(2*m2,     gA, gB);
    step(2*m2 + 1, gB, gA);
  }

  #pragma unroll
  for (int reg = 0; reg < 4; ++reg)
    last[((size_t)run*NSEQ + pair*16 + q*4 + reg)*D_ + j] = hf[reg];
}

// =====================================================================
// visit-level GRU v3 (vgi fused) — verified, unchanged.
// =====================================================================
__global__ __launch_bounds__(768) void k_vgru(
    const float* __restrict__ last, const float* __restrict__ xe,
    const float* __restrict__ wihTv, const float* __restrict__ vbih,
    const float* __restrict__ vWhh, const float* __restrict__ vbhh,
    float* __restrict__ vh)
{
  int run = blockIdx.x >> 4, b = blockIdx.x & 15;
  int tid = threadIdx.x;
  int vidx = (run < 4) ? 0 : (run < 8) ? 1 : (run - 6);

  __shared__ float Xs[16][128];          // 8 KB
  __shared__ float giL[16*384];          // 24 KB
  __shared__ __align__(16) float hsv[128];
  __shared__ float gh[384];

  const float* X = (run < 8) ? (last + ((size_t)run*NSEQ + b*16)*D_)
                             : (xe + ((size_t)(run-8)*NSEQ + b*16)*D_);
  for (int idx = tid; idx < 2048; idx += 768)
    ((float*)Xs)[idx] = X[idx];
  if (tid < 128) hsv[tid] = 0.f;
  __syncthreads();

  // ---- gi precompute into LDS: thread (half, j) does 8 visits ----
  {
    int half = (tid >= 384) ? 1 : 0;
    int j = tid - half*384;
    float accv[8];
    float bias = vbih[vidx*384 + j];
    #pragma unroll
    for (int s = 0; s < 8; ++s) accv[s] = bias;
    const float* W = wihTv + vidx*49152 + j;
    #pragma unroll 4
    for (int k = 0; k < 128; ++k) {
      float wv = W[k*384];
      #pragma unroll
      for (int s = 0; s < 8; ++s) accv[s] += Xs[half*8 + s][k] * wv;
    }
    #pragma unroll
    for (int s = 0; s < 8; ++s)
      giL[(half*8 + s)*384 + j] = accv[s];
  }

  // ---- recurrence weights (pair-split, w[64]/thread, no spill) ----
  int j = tid >> 1, kh = tid & 1;
  float w[64];
  const float4* wrow = (const float4*)(vWhh + (vidx*384 + j)*128 + kh*64);
  #pragma unroll
  for (int k4 = 0; k4 < 16; ++k4) {
    float4 t4 = wrow[k4];
    w[4*k4] = t4.x; w[4*k4+1] = t4.y; w[4*k4+2] = t4.z; w[4*k4+3] = t4.w;
  }
  float bj = vbhh[vidx*384 + j];
  __syncthreads();

  #pragma unroll 1
  for (int v = 0; v < 16; ++v) {
    const float4* h4 = (const float4*)(hsv + kh*64);
    float p0 = 0.f, p1 = 0.f;
    #pragma unroll
    for (int k4 = 0; k4 < 8; ++k4) {
      float4 u0 = h4[k4], u1 = h4[k4+8];
      p0 += w[4*k4   ]*u0.x + w[4*k4+1 ]*u0.y + w[4*k4+2 ]*u0.z + w[4*k4+3 ]*u0.w;
      p1 += w[4*k4+32]*u1.x + w[4*k4+33]*u1.y + w[4*k4+34]*u1.z + w[4*k4+35]*u1.w;
    }
    float part = p0 + p1;
    part += __shfl_xor(part, 1);
    if (kh == 0) gh[j] = bj + ((j < 256) ? giL[v*384 + j] : 0.f) + part;
    __syncthreads();
    if (tid < 128) {
      float r = fsig(gh[tid]);
      float z = fsig(gh[tid+128]);
      float gin = giL[v*384 + 256 + tid];
      float n = ftanh(gin + r*gh[tid+256]);
      hsv[tid] = (1.f - z)*n + z*hsv[tid];
    }
    __syncthreads();
  }
  if (tid < 128) vh[(run*16 + b)*D_ + tid] = hsv[tid];
}

// =====================================================================
// head v4 (pe fused) — verified, unchanged.
// =====================================================================
__global__ __launch_bounds__(256) void k_head(
    const float* __restrict__ vh, const float* __restrict__ Wp,
    const float* __restrict__ bp, float* __restrict__ out)
{
  const int o = blockIdx.x;
  const int tid = threadIdx.x;
  const int b = tid & 15, kc = tid >> 4;
  const int a1[7] = {0,1,2,3,4,8,9};
  const int a2[7] = {-1,5,6,7,-1,-1,-1};
  const float4* wb = (const float4*)(Wp + (size_t)o*896 + kc*56);
  float acc = 0.f;
  #pragma unroll
  for (int i = 0; i < 14; ++i) {
    int cc2 = kc*56 + i*4;
    int s = cc2 >> 7, d0 = cc2 & 127;
    float4 a = *(const float4*)(vh + (a1[s]*16 + b)*D_ + d0);
    int s2 = a2[s];
    if (s2 >= 0) {
      float4 a2v = *(const float4*)(vh + (s2*16 + b)*D_ + d0);
      a.x += a2v.x; a.y += a2v.y; a.z += a2v.z; a.w += a2v.w;
    }
    a.x = fmaxf(a.x, 0.f); a.y = fmaxf(a.y, 0.f);
    a.z = fmaxf(a.z, 0.f); a.w = fmaxf(a.w, 0.f);
    float4 ww = wb[i];
    acc += a.x*ww.x + a.y*ww.y + a.z*ww.z + a.w*ww.w;
  }
  __shared__ float red[16][17];
  red[kc][b] = acc;
  __syncthreads();
  if (tid < 16) {
    float s = 0.f;
    #pragma unroll
    for (int k = 0; k < 16; ++k) s += red[k][tid];
    out[tid*OUT_ + o] = s + bp[o];
  }
}

// =====================================================================
extern "C" void kernel_launch(void* const* d_in, const int* in_sizes, int n_in,
                              void* d_out, int out_size, void* d_ws, size_t ws_size,
                              hipStream_t stream)
{
  (void)in_sizes; (void)n_in; (void)out_size; (void)ws_size;
  const int*   cc   = (const int*)  d_in[0];
  const int*   cp   = (const int*)  d_in[1];
  const int*   cd   = (const int*)  d_in[2];
  const int*   cli  = (const int*)  d_in[3];
  const int*   clv  = (const int*)  d_in[4];
  const int*   cii  = (const int*)  d_in[5];
  const int*   civ  = (const int*)  d_in[6];
  const float* wgt  = (const float*)d_in[7];
  const float* age  = (const float*)d_in[8];
  const float* ec   = (const float*)d_in[9];
  const float* ep   = (const float*)d_in[10];
  const float* ed   = (const float*)d_in[11];
  const float* eli  = (const float*)d_in[12];
  const float* elv  = (const float*)d_in[13];
  const float* eii  = (const float*)d_in[14];
  const float* eiv  = (const float*)d_in[15];
  const float* mWih = (const float*)d_in[16];
  const float* mWhh = (const float*)d_in[17];
  const float* mbih = (const float*)d_in[18];
  const float* mbhh = (const float*)d_in[19];
  const float* vWih = (const float*)d_in[20];
  const float* vWhh = (const float*)d_in[21];
  const float* vbih = (const float*)d_in[22];
  const float* vbhh = (const float*)d_in[23];
  const float* Wself= (const float*)d_in[24];
  const float* Wmsg = (const float*)d_in[25];
  const float* fwW  = (const float*)d_in[26];
  const float* fwB  = (const float*)d_in[27];
  const float* faW  = (const float*)d_in[28];
  const float* faB  = (const float*)d_in[29];
  const float* Wp   = (const float*)d_in[30];
  const float* bp   = (const float*)d_in[31];
  float* out = (float*)d_out;
  float* ws  = (float*)d_ws;

  float* vis   = ws + OFF_VIS;
  short* visb  = (short*)(ws + OFF_VISB);
  short* monb  = (short*)(ws + OFF_MONB);
  short* totb  = (short*)(ws + OFF_TOTB);
  short* w12t  = (short*)(ws + OFF_W12T);
  short* wihb  = (short*)(ws + OFF_WIHB);
  float* wihTv = ws + OFF_WIHTV;
  float* xe    = ws + OFF_XE;
  short* gi    = (short*)(ws + OFF_GI);
  float* last  = ws + OFF_LAST;
  float* vh    = ws + OFF_VH;

  k_prepvis<<<3392, 256, 0, stream>>>(Wself, Wmsg, mWih, vWih, wgt, age,
                                      fwW, fwB, faW, faB,
                                      cc, cp, cd, ec, ep, ed,
                                      w12t, wihb, wihTv, xe, vis, visb);
  k_mon <<<16384, 128, 0, stream>>>(cli, clv, cii, civ, eli, elv, eii, eiv,
                                    vis, monb, totb);
  k_gg  <<<512, 256, 0, stream>>>(monb, totb, visb, w12t, wihb, mbih, gi);
  k_mgru<<<128, 512, 0, stream>>>(gi, mWhh, mbhh, last);
  k_vgru<<<160, 768, 0, stream>>>(last, xe, wihTv, vbih, vWhh, vbhh, vh);
  k_head<<<600, 256, 0, stream>>>(vh, Wp, bp, out);
}

// Round 4
// 266.852 us; speedup vs baseline: 1.0523x; 1.0068x over previous
//
#include <hip/hip_runtime.h>
#include <math.h>

#define B_   16
#define V_   16
#define C_   64
#define M_   32
#define CM_  16
#define D_   128
#define OUT_ 600
#define NSEQ 256      // B*V
#define NROW 8192     // B*V*M

typedef __attribute__((ext_vector_type(8))) short bf16x8;
typedef __attribute__((ext_vector_type(4))) short bf16x4;
typedef __attribute__((ext_vector_type(4))) float f32x4;
typedef __attribute__((ext_vector_type(2))) unsigned int u32x2;

__device__ __forceinline__ unsigned short f2bf(float x) {
  union { float f; unsigned u; } v; v.f = x;
  unsigned r = v.u + 0x7fff + ((v.u >> 16) & 1);   // RNE
  return (unsigned short)(r >> 16);
}
__device__ __forceinline__ float bf2f(short s) {
  union { unsigned u; float f; } v;
  v.u = ((unsigned)(unsigned short)s) << 16;
  return v.f;
}
__device__ __forceinline__ float u2f(unsigned u) {
  union { unsigned u; float f; } v; v.u = u; return v.f;
}
// fast sigmoid / tanh: native v_exp + v_rcp (~5 inst), saturate correctly
__device__ __forceinline__ float fsig(float x)  { return __fdividef(1.f, 1.f + __expf(-x)); }
__device__ __forceinline__ float ftanh(float x) { return 1.f - 2.f*__fdividef(1.f, __expf(2.f*x) + 1.f); }

// LDS-only barrier: drains LDS ops for cross-wave visibility but does NOT
// drain vmcnt — in-flight global (gi prefetch) loads survive the barrier.
__device__ __forceinline__ void ldsbar() {
  asm volatile("s_waitcnt lgkmcnt(0)" ::: "memory");
  __builtin_amdgcn_s_barrier();
  asm volatile("" ::: "memory");
}

// manual 8B global load (2 dwords) — keeps waitcnt control OUT of the
// compiler's hands; paired with explicit counted s_waitcnt vmcnt(N).
#define GLD(dst, ptr, offstr) \
  asm volatile("global_load_dwordx2 %0, %1, off offset:" offstr \
               : "=v"(dst) : "v"(ptr) : "memory")

// ---- workspace layout (float units; bf16 arrays are short* views) ----
constexpr int OFF_VIS   = 0;                               // fp32 [3][256][128]
constexpr int OFF_VISB  = 98304;                           // bf16 [3][256][128]
constexpr int OFF_MONB  = 147456;                          // bf16 [2][8192][128]
constexpr int OFF_TOTB  = 1196032;                         // bf16 [2][8192][128]
constexpr int OFF_W12T  = 2244608;                         // bf16 [8][128n][256k]
constexpr int OFF_WIHB  = 2375680;                         // bf16 [5][384n][128k]
constexpr int OFF_WIHTV = 2498560;                         // fp32 [4][128][384]
constexpr int OFF_XE    = 2695168;                         // fp32 [2][256][128]
constexpr int OFF_GI    = 2760704;                         // bf16 gi3[8][64][32][384][4]
constexpr int OFF_LAST  = 27926528;                        // fp32 [8][256][128]
constexpr int OFF_VH    = 29171712;                        // fp32 [10][16][128]

// =====================================================================
// prep+vis merged — verified, unchanged.
// =====================================================================
__global__ __launch_bounds__(256) void k_prepvis(
    const float* __restrict__ Wself, const float* __restrict__ Wmsg,
    const float* __restrict__ mWih,  const float* __restrict__ vWih,
    const float* __restrict__ wgt,   const float* __restrict__ age,
    const float* __restrict__ fwW,   const float* __restrict__ fwB,
    const float* __restrict__ faW,   const float* __restrict__ faB,
    const int* __restrict__ cc, const int* __restrict__ cp, const int* __restrict__ cd,
    const float* __restrict__ ec, const float* __restrict__ ep, const float* __restrict__ ed,
    short* __restrict__ w12t, short* __restrict__ wihb,
    float* __restrict__ wihTv, float* __restrict__ xe,
    float* __restrict__ vis, short* __restrict__ visb)
{
  int bx = blockIdx.x, tid = threadIdx.x;
  if (bx < 1024) {                      // w12t[pt][n][k] = bf16 combined
    int lin = bx*256 + tid;             // < 262144
    int pt = lin >> 15, rem = lin & 32767;
    int n = rem >> 8, k = rem & 255;
    float v;
    if (k < 128) v = Wself[pt*16384 + k*128 + n] - Wmsg[pt*16384 + k*128 + n]*(1.f/3.f);
    else         v = Wmsg[pt*16384 + (k-128)*128 + n]*(1.f/3.f);
    w12t[lin] = (short)f2bf(v);
  } else if (bx < 1984) {               // wihb = bf16(mWih) elementwise
    int lin = (bx-1024)*256 + tid;      // < 245760
    wihb[lin] = (short)f2bf(mWih[lin]);
  } else if (bx < 2752) {               // vgru Wih transpose fp32
    int lin = (bx-1984)*256 + tid;      // < 196608
    int g = lin / 49152, rem2 = lin % 49152;
    int k = rem2 / 384, j = rem2 % 384;
    wihTv[lin] = vWih[g*49152 + j*128 + k];
  } else if (bx < 3008) {               // xe for weight / age
    int lin = (bx-2752)*256 + tid;      // < 65536
    int which = lin >> 15, rem2 = lin & 32767;
    int n = rem2 >> 7, d = rem2 & 127;
    float x  = which ? age[n] : wgt[n];
    float Wv = which ? faW[d] : fwW[d];
    float bb = which ? faB[d] : fwB[d];
    xe[lin] = (x != 0.0f) ? (x*Wv + bb) : 0.0f;
  } else {                              // visit-event sum pools
    int idx = (bx-3008)*256 + tid;      // < 98304
    int type = idx >> 15;
    int r = idx & 32767;
    int bv = r >> 7, d = r & 127;
    const int*   codes = (type==0) ? cc : (type==1) ? cp : cd;
    const float* emb   = (type==0) ? ec : (type==1) ? ep : ed;
    float acc = 0.f;
    for (int c = 0; c < C_; ++c) {
      int code = codes[bv*C_ + c];
      acc += emb[code*D_ + d];
    }
    vis [(type*NSEQ + bv)*D_ + d] = acc;
    visb[(type*NSEQ + bv)*D_ + d] = (short)f2bf(acc);
  }
}

// =====================================================================
// monitor-event pools — unchanged (verified).
// =====================================================================
__global__ __launch_bounds__(128) void k_mon(
    const int* __restrict__ cli, const int* __restrict__ clv,
    const int* __restrict__ cii, const int* __restrict__ civ,
    const float* __restrict__ eli, const float* __restrict__ elv,
    const float* __restrict__ eii, const float* __restrict__ eiv,
    const float* __restrict__ vis,
    short* __restrict__ monb, short* __restrict__ totb)
{
  int p   = blockIdx.x >> 13;
  int bvm = blockIdx.x & 8191;
  int d   = threadIdx.x;
  const int* ci = p ? cii : cli;  const int* cv = p ? civ : clv;
  const float* ei = p ? eii : eli; const float* ev = p ? eiv : elv;
  float acc = 0.f;
  #pragma unroll
  for (int c = 0; c < CM_; ++c) {
    int iv = ci[bvm*CM_ + c];
    int vv = cv[bvm*CM_ + c];
    acc += ei[iv*D_ + d] * ev[vv*D_ + d];
  }
  int bv = bvm >> 5;
  float vsum = vis[bv*D_ + d] + vis[(NSEQ + bv)*D_ + d] + vis[(2*NSEQ + bv)*D_ + d];
  monb[(p*NROW + bvm)*D_ + d] = (short)f2bf(acc);
  totb[(p*NROW + bvm)*D_ + d] = (short)f2bf(acc + vsum);
}

// =====================================================================
// FUSED GNN+GI (MFMA bf16) — verified, unchanged.
// =====================================================================
__global__ __launch_bounds__(256, 4) void k_gg(
    const short* __restrict__ monb, const short* __restrict__ totb,
    const short* __restrict__ visb, const short* __restrict__ w12t,
    const short* __restrict__ wihb, const float* __restrict__ mbih,
    short* __restrict__ gi)
{
  const int pt = blockIdx.x >> 6;          // run 0..7
  const int rb = blockIdx.x & 63;
  const int p = pt >> 2, t = pt & 3;
  const int g = (pt % 4 == 0) ? (pt / 4) : (pt % 4 + 1);
  const int row0 = rb * 128;
  const int tid = threadIdx.x;
  const int w = tid >> 6, lane = tid & 63;
  const int c = lane & 15, q = lane >> 4;

  __shared__ short smem[2*128*72];         // 36864 B; Ys / giS alias
  short (*Xs)[72]  = (short(*)[72])smem;
  short (*Ws)[72]  = (short(*)[72])(smem + 128*72);
  short (*Ys)[136] = (short(*)[136])smem;
  float (*giS)[68] = (float(*)[68])smem;   // 128 x 68 fp32 = 34816 B

  const int rowL = tid >> 1, kc = tid & 1;
  const int rowG = row0 + rowL;
  const int bv = rowG >> 5;
  const int mg = w >> 1, ng = w & 1;

  f32x4 acc1[4][4];
  #pragma unroll
  for (int mi = 0; mi < 4; ++mi)
    #pragma unroll
    for (int ni = 0; ni < 4; ++ni) acc1[mi][ni] = (f32x4){0.f,0.f,0.f,0.f};

  const short* featp = (t == 0) ? (monb + ((size_t)p*NROW + rowG)*128)
                                : (visb + ((size_t)(t-1)*NSEQ + bv)*128);
  const short* totp  = totb + ((size_t)p*NROW + rowG)*128;
  const short* wrow  = w12t + ((size_t)pt*128 + rowL)*256;

  #pragma unroll 1
  for (int ks = 0; ks < 4; ++ks) {
    __syncthreads();
    int kg = ks*64 + kc*32;
    const short* srcX = (kg < 128) ? (featp + kg) : (totp + (kg - 128));
    const short* srcW = wrow + kg;
    short* dX = &Xs[rowL][kc*32];
    short* dW = &Ws[rowL][kc*32];
    #pragma unroll
    for (int i = 0; i < 4; ++i) {
      *(bf16x8*)(dX + 8*i) = *(const bf16x8*)(srcX + 8*i);
      *(bf16x8*)(dW + 8*i) = *(const bf16x8*)(srcW + 8*i);
    }
    __syncthreads();
    #pragma unroll
    for (int kk = 0; kk < 2; ++kk) {
      bf16x8 af[4], bfr[4];
      #pragma unroll
      for (int mi = 0; mi < 4; ++mi)
        af[mi] = *(const bf16x8*)&Xs[(mg*4+mi)*16 + c][kk*32 + q*8];
      #pragma unroll
      for (int ni = 0; ni < 4; ++ni)
        bfr[ni] = *(const bf16x8*)&Ws[(ng*4+ni)*16 + c][kk*32 + q*8];
      #pragma unroll
      for (int mi = 0; mi < 4; ++mi)
        #pragma unroll
        for (int ni = 0; ni < 4; ++ni)
          acc1[mi][ni] = __builtin_amdgcn_mfma_f32_16x16x32_bf16(af[mi], bfr[ni], acc1[mi][ni], 0, 0, 0);
    }
  }
  __syncthreads();     // done reading Xs/Ws (Ys aliases them)

  // relu + C-layout (col=lane&15, row=(lane>>4)*4+reg) -> Ys[row][col] bf16
  #pragma unroll
  for (int mi = 0; mi < 4; ++mi)
    #pragma unroll
    for (int ni = 0; ni < 4; ++ni)
      #pragma unroll
      for (int reg = 0; reg < 4; ++reg)
        Ys[(mg*4+mi)*16 + q*4 + reg][(ng*4+ni)*16 + c] =
            (short)f2bf(fmaxf(acc1[mi][ni][reg], 0.f));
  __syncthreads();

  // ---- stage 2: gi = Y @ Wih^T + bih ----
  bf16x8 Af[2][4];
  #pragma unroll
  for (int mi = 0; mi < 2; ++mi)
    #pragma unroll
    for (int kt = 0; kt < 4; ++kt)
      Af[mi][kt] = *(const bf16x8*)&Ys[(w*2+mi)*16 + c][kt*32 + q*8];

  float bihv[24];
  #pragma unroll
  for (int nt = 0; nt < 24; ++nt)
    bihv[nt] = mbih[g*384 + nt*16 + c];

  short* gslab = gi + (((size_t)pt*64 + rb)*32)*384*4;   // bf16 [m][col][s4]
  #pragma unroll 1
  for (int cn = 0; cn < 6; ++cn) {
    f32x4 acc2[2][4];
    #pragma unroll
    for (int mi = 0; mi < 2; ++mi)
      #pragma unroll
      for (int ni = 0; ni < 4; ++ni) acc2[mi][ni] = (f32x4){0.f,0.f,0.f,0.f};
    #pragma unroll
    for (int ni = 0; ni < 4; ++ni) {
      int n = (cn*4 + ni)*16 + c;
      const short* bp_ = wihb + ((size_t)g*384 + n)*128 + q*8;
      #pragma unroll
      for (int kt = 0; kt < 4; ++kt) {
        bf16x8 bfr = *(const bf16x8*)(bp_ + kt*32);
        #pragma unroll
        for (int mi = 0; mi < 2; ++mi)
          acc2[mi][ni] = __builtin_amdgcn_mfma_f32_16x16x32_bf16(Af[mi][kt], bfr, acc2[mi][ni], 0, 0, 0);
      }
    }
    __syncthreads();
    #pragma unroll
    for (int mi = 0; mi < 2; ++mi)
      #pragma unroll
      for (int ni = 0; ni < 4; ++ni) {
        float bia = bihv[cn*4+ni];
        #pragma unroll
        for (int reg = 0; reg < 4; ++reg)
          giS[(w*2+mi)*16 + q*4 + reg][ni*16 + c] = acc2[mi][ni][reg] + bia;
      }
    __syncthreads();
    #pragma unroll
    for (int k = 0; k < 8; ++k) {
      int o4 = tid + k*256;            // 0..2047
      int m = o4 >> 6, colL = o4 & 63;
      bf16x4 v;
      v[0] = (short)f2bf(giS[m][colL]);
      v[1] = (short)f2bf(giS[32+m][colL]);
      v[2] = (short)f2bf(giS[64+m][colL]);
      v[3] = (short)f2bf(giS[96+m][colL]);
      *(bf16x4*)&gslab[((size_t)m*384 + cn*64 + colL)*4] = v;
    }
  }
}

// =====================================================================
// monitor-level GRU v8.1 — THIS ROUND: gi prefetch via inline-asm
// global_load_dwordx2 into a 3-deep rotating register buffer with
// EXPLICIT counted s_waitcnt vmcnt(6) (T4). In the steady loop these
// are the only vmem ops, so the counted wait is exact: issue for step
// m+2 during step m, 6 loads in flight, load-to-use = 2 steps. The
// compiler can no longer drain vmcnt(0) at the use site.
// Structure otherwise identical to verified v8.
// =====================================================================
__global__ __launch_bounds__(512, 2) void k_mgru(
    const short* __restrict__ gi, const float* __restrict__ mWhh,
    const float* __restrict__ mbhh, float* __restrict__ last)
{
  const int run  = blockIdx.x >> 4;     // 0..7
  const int pair = blockIdx.x & 15;     // 0..15 (16 seqs per block)
  const int g = (run % 4 == 0) ? (run / 4) : (run % 4 + 1);
  const int tid = threadIdx.x;
  const int w = tid >> 6;               // wave 0..7 = hidden slice
  const int lane = tid & 63;
  const int c = lane & 15, q = lane >> 4;
  const int j = w*16 + c;               // hidden index 0..127

  __shared__ short hb[2][4][16][40];    // [buf][kt][seq][kk+pad] bf16, 10240 B

  for (int idx = tid; idx < 2*4*16*40; idx += 512)
    ((short*)hb)[idx] = 0;

  // ---- B fragments in registers: Whh rows for cols gate*128+j ----
  bf16x8 bfrag[3][4];
  #pragma unroll
  for (int gate = 0; gate < 3; ++gate) {
    const float* wp = mWhh + ((size_t)g*384 + gate*128 + j)*128 + q*8;
    #pragma unroll
    for (int kt = 0; kt < 4; ++kt) {
      float4 lo = *(const float4*)(wp + kt*32);
      float4 hi = *(const float4*)(wp + kt*32 + 4);
      bf16x8 t;
      t[0]=(short)f2bf(lo.x); t[1]=(short)f2bf(lo.y); t[2]=(short)f2bf(lo.z); t[3]=(short)f2bf(lo.w);
      t[4]=(short)f2bf(hi.x); t[5]=(short)f2bf(hi.y); t[6]=(short)f2bf(hi.z); t[7]=(short)f2bf(hi.w);
      bfrag[gate][kt] = t;
    }
  }
  const float bh0 = mbhh[g*384 +       j];
  const float bh1 = mbhh[g*384 + 128 + j];
  const float bh2 = mbhh[g*384 + 256 + j];

  // gi slab for this lane's seq-quad q; lane's element base = j*4 shorts.
  // step m, gate gt: gib[(m*1536) + (gt*128+j)*4 + s]  (s = 0..3 in bf16x4)
  const short* gib = gi + ((size_t)((run*64 + pair*4 + q)*32))*1536;
  const short* gpl = gib + j*4;         // lane base; gate offset = 1024 B

  float hf[4] = {0.f,0.f,0.f,0.f};
  const int ktw = w >> 1;               // j>>5
  const int kkw = (w & 1)*16 + c;       // j&31

  // 3-deep rotating prefetch buffers (3 gates x 8B each)
  u32x2 g0[3], g1[3], g2[3];
  // prologue: issue steps 0 and 1
  GLD(g0[0], gpl,        "0");
  GLD(g0[1], gpl,        "1024");
  GLD(g0[2], gpl,        "2048");
  GLD(g1[0], gpl + 1536, "0");
  GLD(g1[1], gpl + 1536, "1024");
  GLD(g1[2], gpl + 1536, "2048");
  const short* gpn = gpl + 2*1536;      // next issue pointer (step m+2)

  ldsbar();   // hb zero-init visible; prefetches stay in flight

  // wsel: 0 = steady (issue next+2, wait vmcnt(6))
  //       1 = step 30 (no issue, wait vmcnt(3))
  //       2 = step 31 (no issue, wait vmcnt(0))
  auto step = [&](int m, u32x2 (&gcur)[3], u32x2 (&giss)[3], int wsel) {
    const int cur = m & 1, nxt = cur ^ 1;
    // h(m-1) fragments: A[row=seq=c][k = kt*32 + q*8 + i]
    bf16x8 a[4];
    #pragma unroll
    for (int kt = 0; kt < 4; ++kt)
      a[kt] = *(const bf16x8*)&hb[cur][kt][c][q*8];
    // 3 gates x K=128 for this wave's 16 cols
    f32x4 acc[3];
    #pragma unroll
    for (int gate = 0; gate < 3; ++gate) {
      f32x4 t = {0.f,0.f,0.f,0.f};
      #pragma unroll
      for (int kt = 0; kt < 4; ++kt)
        t = __builtin_amdgcn_mfma_f32_16x16x32_bf16(a[kt], bfrag[gate][kt], t, 0, 0, 0);
      acc[gate] = t;
    }
    // issue step m+2's gi loads (counted, never drained to 0 in-loop)
    if (wsel == 0) {
      GLD(giss[0], gpn, "0");
      GLD(giss[1], gpn, "1024");
      GLD(giss[2], gpn, "2048");
      gpn += 1536;
    }
    // wait for step m's loads only (6 newer stay in flight)
    if (wsel == 0)      asm volatile("s_waitcnt vmcnt(6)" ::: "memory");
    else if (wsel == 1) asm volatile("s_waitcnt vmcnt(3)" ::: "memory");
    else                asm volatile("s_waitcnt vmcnt(0)" ::: "memory");
    __builtin_amdgcn_sched_barrier(0);
    // unpack bf16x4 (4 seqs) per gate
    float ga[3][4];
    #pragma unroll
    for (int gate = 0; gate < 3; ++gate) {
      ga[gate][0] = u2f(gcur[gate].x << 16);
      ga[gate][1] = u2f(gcur[gate].x & 0xffff0000u);
      ga[gate][2] = u2f(gcur[gate].y << 16);
      ga[gate][3] = u2f(gcur[gate].y & 0xffff0000u);
    }
    // lane-local GRU activation: (seq = q*4+reg, this j)
    #pragma unroll
    for (int reg = 0; reg < 4; ++reg) {
      float rr = fsig(acc[0][reg] + bh0 + ga[0][reg]);
      float zz = fsig(acc[1][reg] + bh1 + ga[1][reg]);
      float nn = ftanh(ga[2][reg] + rr*(acc[2][reg] + bh2));
      float hnew = (1.f - zz)*nn + zz*hf[reg];
      hf[reg] = hnew;
      hb[nxt][ktw][q*4 + reg][kkw] = (short)f2bf(hnew);
    }
    ldsbar();   // h(m) visible for step m+1; prefetches stay in flight
  };

  // steps 0..29: buffer rotation period 3, superloop of 6 steps
  #pragma unroll 1
  for (int mb = 0; mb < 30; mb += 6) {
    step(mb+0, g0, g2, 0);
    step(mb+1, g1, g0, 0);
    step(mb+2, g2, g1, 0);
    step(mb+3, g0, g2, 0);
    step(mb+4, g1, g0, 0);
    step(mb+5, g2, g1, 0);
  }
  step(30, g0, g2, 1);
  step(31, g1, g0, 2);

  #pragma unroll
  for (int reg = 0; reg < 4; ++reg)
    last[((size_t)run*NSEQ + pair*16 + q*4 + reg)*D_ + j] = hf[reg];
}

// =====================================================================
// visit-level GRU v3 (vgi fused) — verified, unchanged.
// =====================================================================
__global__ __launch_bounds__(768) void k_vgru(
    const float* __restrict__ last, const float* __restrict__ xe,
    const float* __restrict__ wihTv, const float* __restrict__ vbih,
    const float* __restrict__ vWhh, const float* __restrict__ vbhh,
    float* __restrict__ vh)
{
  int run = blockIdx.x >> 4, b = blockIdx.x & 15;
  int tid = threadIdx.x;
  int vidx = (run < 4) ? 0 : (run < 8) ? 1 : (run - 6);

  __shared__ float Xs[16][128];          // 8 KB
  __shared__ float giL[16*384];          // 24 KB
  __shared__ __align__(16) float hsv[128];
  __shared__ float gh[384];

  const float* X = (run < 8) ? (last + ((size_t)run*NSEQ + b*16)*D_)
                             : (xe + ((size_t)(run-8)*NSEQ + b*16)*D_);
  for (int idx = tid; idx < 2048; idx += 768)
    ((float*)Xs)[idx] = X[idx];
  if (tid < 128) hsv[tid] = 0.f;
  __syncthreads();

  // ---- gi precompute into LDS: thread (half, j) does 8 visits ----
  {
    int half = (tid >= 384) ? 1 : 0;
    int j = tid - half*384;
    float accv[8];
    float bias = vbih[vidx*384 + j];
    #pragma unroll
    for (int s = 0; s < 8; ++s) accv[s] = bias;
    const float* W = wihTv + vidx*49152 + j;
    #pragma unroll 4
    for (int k = 0; k < 128; ++k) {
      float wv = W[k*384];
      #pragma unroll
      for (int s = 0; s < 8; ++s) accv[s] += Xs[half*8 + s][k] * wv;
    }
    #pragma unroll
    for (int s = 0; s < 8; ++s)
      giL[(half*8 + s)*384 + j] = accv[s];
  }

  // ---- recurrence weights (pair-split, w[64]/thread, no spill) ----
  int j = tid >> 1, kh = tid & 1;
  float w[64];
  const float4* wrow = (const float4*)(vWhh + (vidx*384 + j)*128 + kh*64);
  #pragma unroll
  for (int k4 = 0; k4 < 16; ++k4) {
    float4 t4 = wrow[k4];
    w[4*k4] = t4.x; w[4*k4+1] = t4.y; w[4*k4+2] = t4.z; w[4*k4+3] = t4.w;
  }
  float bj = vbhh[vidx*384 + j];
  __syncthreads();

  #pragma unroll 1
  for (int v = 0; v < 16; ++v) {
    const float4* h4 = (const float4*)(hsv + kh*64);
    float p0 = 0.f, p1 = 0.f;
    #pragma unroll
    for (int k4 = 0; k4 < 8; ++k4) {
      float4 u0 = h4[k4], u1 = h4[k4+8];
      p0 += w[4*k4   ]*u0.x + w[4*k4+1 ]*u0.y + w[4*k4+2 ]*u0.z + w[4*k4+3 ]*u0.w;
      p1 += w[4*k4+32]*u1.x + w[4*k4+33]*u1.y + w[4*k4+34]*u1.z + w[4*k4+35]*u1.w;
    }
    float part = p0 + p1;
    part += __shfl_xor(part, 1);
    if (kh == 0) gh[j] = bj + ((j < 256) ? giL[v*384 + j] : 0.f) + part;
    __syncthreads();
    if (tid < 128) {
      float r = fsig(gh[tid]);
      float z = fsig(gh[tid+128]);
      float gin = giL[v*384 + 256 + tid];
      float n = ftanh(gin + r*gh[tid+256]);
      hsv[tid] = (1.f - z)*n + z*hsv[tid];
    }
    __syncthreads();
  }
  if (tid < 128) vh[(run*16 + b)*D_ + tid] = hsv[tid];
}

// =====================================================================
// head v4 (pe fused) — verified, unchanged.
// =====================================================================
__global__ __launch_bounds__(256) void k_head(
    const float* __restrict__ vh, const float* __restrict__ Wp,
    const float* __restrict__ bp, float* __restrict__ out)
{
  const int o = blockIdx.x;
  const int tid = threadIdx.x;
  const int b = tid & 15, kc = tid >> 4;
  const int a1[7] = {0,1,2,3,4,8,9};
  const int a2[7] = {-1,5,6,7,-1,-1,-1};
  const float4* wb = (const float4*)(Wp + (size_t)o*896 + kc*56);
  float acc = 0.f;
  #pragma unroll
  for (int i = 0; i < 14; ++i) {
    int cc2 = kc*56 + i*4;
    int s = cc2 >> 7, d0 = cc2 & 127;
    float4 a = *(const float4*)(vh + (a1[s]*16 + b)*D_ + d0);
    int s2 = a2[s];
    if (s2 >= 0) {
      float4 a2v = *(const float4*)(vh + (s2*16 + b)*D_ + d0);
      a.x += a2v.x; a.y += a2v.y; a.z += a2v.z; a.w += a2v.w;
    }
    a.x = fmaxf(a.x, 0.f); a.y = fmaxf(a.y, 0.f);
    a.z = fmaxf(a.z, 0.f); a.w = fmaxf(a.w, 0.f);
    float4 ww = wb[i];
    acc += a.x*ww.x + a.y*ww.y + a.z*ww.z + a.w*ww.w;
  }
  __shared__ float red[16][17];
  red[kc][b] = acc;
  __syncthreads();
  if (tid < 16) {
    float s = 0.f;
    #pragma unroll
    for (int k = 0; k < 16; ++k) s += red[k][tid];
    out[tid*OUT_ + o] = s + bp[o];
  }
}

// =====================================================================
extern "C" void kernel_launch(void* const* d_in, const int* in_sizes, int n_in,
                              void* d_out, int out_size, void* d_ws, size_t ws_size,
                              hipStream_t stream)
{
  (void)in_sizes; (void)n_in; (void)out_size; (void)ws_size;
  const int*   cc   = (const int*)  d_in[0];
  const int*   cp   = (const int*)  d_in[1];
  const int*   cd   = (const int*)  d_in[2];
  const int*   cli  = (const int*)  d_in[3];
  const int*   clv  = (const int*)  d_in[4];
  const int*   cii  = (const int*)  d_in[5];
  const int*   civ  = (const int*)  d_in[6];
  const float* wgt  = (const float*)d_in[7];
  const float* age  = (const float*)d_in[8];
  const float* ec   = (const float*)d_in[9];
  const float* ep   = (const float*)d_in[10];
  const float* ed   = (const float*)d_in[11];
  const float* eli  = (const float*)d_in[12];
  const float* elv  = (const float*)d_in[13];
  const float* eii  = (const float*)d_in[14];
  const float* eiv  = (const float*)d_in[15];
  const float* mWih = (const float*)d_in[16];
  const float* mWhh = (const float*)d_in[17];
  const float* mbih = (const float*)d_in[18];
  const float* mbhh = (const float*)d_in[19];
  const float* vWih = (const float*)d_in[20];
  const float* vWhh = (const float*)d_in[21];
  const float* vbih = (const float*)d_in[22];
  const float* vbhh = (const float*)d_in[23];
  const float* Wself= (const float*)d_in[24];
  const float* Wmsg = (const float*)d_in[25];
  const float* fwW  = (const float*)d_in[26];
  const float* fwB  = (const float*)d_in[27];
  const float* faW  = (const float*)d_in[28];
  const float* faB  = (const float*)d_in[29];
  const float* Wp   = (const float*)d_in[30];
  const float* bp   = (const float*)d_in[31];
  float* out = (float*)d_out;
  float* ws  = (float*)d_ws;

  float* vis   = ws + OFF_VIS;
  short* visb  = (short*)(ws + OFF_VISB);
  short* monb  = (short*)(ws + OFF_MONB);
  short* totb  = (short*)(ws + OFF_TOTB);
  short* w12t  = (short*)(ws + OFF_W12T);
  short* wihb  = (short*)(ws + OFF_WIHB);
  float* wihTv = ws + OFF_WIHTV;
  float* xe    = ws + OFF_XE;
  short* gi    = (short*)(ws + OFF_GI);
  float* last  = ws + OFF_LAST;
  float* vh    = ws + OFF_VH;

  k_prepvis<<<3392, 256, 0, stream>>>(Wself, Wmsg, mWih, vWih, wgt, age,
                                      fwW, fwB, faW, faB,
                                      cc, cp, cd, ec, ep, ed,
                                      w12t, wihb, wihTv, xe, vis, visb);
  k_mon <<<16384, 128, 0, stream>>>(cli, clv, cii, civ, eli, elv, eii, eiv,
                                    vis, monb, totb);
  k_gg  <<<512, 256, 0, stream>>>(monb, totb, visb, w12t, wihb, mbih, gi);
  k_mgru<<<128, 512, 0, stream>>>(gi, mWhh, mbhh, last);
  k_vgru<<<160, 768, 0, stream>>>(last, xe, wihTv, vbih, vWhh, vbhh, vh);
  k_head<<<600, 256, 0, stream>>>(vh, Wp, bp, out);
}